// Round 1
// baseline (1000.509 us; speedup 1.0000x reference)
//
#include <hip/hip_runtime.h>
#include <math.h>

#define NN 50000
#define EE 800000
#define GG 64
#define FD 128
#define OUTD 10

// ---------------- preprocessing ----------------

__global__ void k_init(float* deg, int* cnt, float* sums, float* cntg, int n) {
    int i = blockIdx.x * blockDim.x + threadIdx.x;
    if (i < n) { deg[i] = 1.0f; cnt[i] = 1; }   // self-loop weight 1, self-loop count 1
    if (i < GG * OUTD) sums[i] = 0.0f;
    if (i < GG) cntg[i] = 0.0f;
}

__global__ void k_degree(const int* __restrict__ dst, const float* __restrict__ w,
                         float* deg, int* cnt, int e) {
    int i = blockIdx.x * blockDim.x + threadIdx.x;
    if (i >= e) return;
    int d = dst[i];
    atomicAdd(&deg[d], w[i]);
    atomicAdd(&cnt[d], 1);
}

__global__ void k_dinv(float* deg, int n) {
    int i = blockIdx.x * blockDim.x + threadIdx.x;
    if (i >= n) return;
    deg[i] = 1.0f / sqrtf(deg[i]);   // deg >= 1 always (self-loop)
}

// single-block exclusive scan of cnt[0..n) -> rowptr, plus copy to fill, rowptr[n]=total
__global__ void k_scan(const int* __restrict__ cnt, int* __restrict__ rowptr,
                       int* __restrict__ fill, int n) {
    __shared__ int wtot[16];
    __shared__ int carry_s;
    int tid = threadIdx.x;
    int lane = tid & 63, wv = tid >> 6;
    if (tid == 0) carry_s = 0;
    __syncthreads();
    for (int base = 0; base < n; base += 1024) {
        int i = base + tid;
        int v = (i < n) ? cnt[i] : 0;
        int s = v;
        #pragma unroll
        for (int off = 1; off < 64; off <<= 1) {
            int u = __shfl_up(s, off, 64);
            if (lane >= off) s += u;
        }
        if (lane == 63) wtot[wv] = s;
        __syncthreads();
        int carry_local = carry_s;
        int wpre = 0;
        for (int j = 0; j < wv; ++j) wpre += wtot[j];
        int excl = carry_local + wpre + (s - v);
        if (i < n) { rowptr[i] = excl; fill[i] = excl; }
        __syncthreads();
        if (tid == 1023) carry_s = excl + v;   // inclusive of last element = new carry
        __syncthreads();
    }
    if (tid == 0) rowptr[n] = carry_s;
}

__global__ void k_fill(const int* __restrict__ src, const int* __restrict__ dst,
                       const float* __restrict__ w, const float* __restrict__ dinv,
                       int* fill, int* __restrict__ col, float* __restrict__ val,
                       int e, int n) {
    int i = blockIdx.x * blockDim.x + threadIdx.x;
    if (i < e) {
        int s = src[i], d = dst[i];
        int pos = atomicAdd(&fill[d], 1);
        col[pos] = s;
        val[pos] = dinv[s] * w[i] * dinv[d];
    } else if (i < e + n) {
        int nd = i - e;
        int pos = atomicAdd(&fill[nd], 1);
        col[pos] = nd;
        val[pos] = dinv[nd] * dinv[nd];
    }
}

// ---------------- dense transforms ----------------

// out[n][128] = A[n][128] @ W[128][128], f32. 64-row tile per block, 256 threads,
// per-thread 4 rows x 8 cols. k staged in chunks of 32 (LDS 24.8 KB -> ~6 blocks/CU).
__global__ __launch_bounds__(256) void k_gemm128(const float* __restrict__ A,
        const float* __restrict__ W, float* __restrict__ out, int n) {
    __shared__ float Ws[32 * 128];
    __shared__ float As[64 * 33];   // +1 pad: bank = (r + k) % 32 -> 2-way max (free)
    int tid = threadIdx.x;
    int row0 = blockIdx.x * 64;
    int rg = tid & 15, cg = tid >> 4;
    int r0 = rg * 4, c0 = cg * 8;
    float acc[4][8];
    #pragma unroll
    for (int i = 0; i < 4; ++i)
        #pragma unroll
        for (int j = 0; j < 8; ++j) acc[i][j] = 0.0f;

    for (int kk = 0; kk < 128; kk += 32) {
        __syncthreads();
        // stage W rows kk..kk+31 (4096 floats) as float4
        for (int i = tid; i < 32 * 128 / 4; i += 256)
            ((float4*)Ws)[i] = ((const float4*)(W + kk * 128))[i];
        // stage A tile chunk: 64 rows x 32 k
        for (int j = tid; j < 64 * 32; j += 256) {
            int r = j >> 5, kl = j & 31;
            float v = 0.0f;
            int row = row0 + r;
            if (row < n) v = A[(size_t)row * 128 + kk + kl];
            As[r * 33 + kl] = v;
        }
        __syncthreads();
        #pragma unroll
        for (int kl = 0; kl < 32; ++kl) {
            float wv[8];
            *(float4*)&wv[0] = *(const float4*)&Ws[kl * 128 + c0];
            *(float4*)&wv[4] = *(const float4*)&Ws[kl * 128 + c0 + 4];
            float av[4];
            #pragma unroll
            for (int i = 0; i < 4; ++i) av[i] = As[(r0 + i) * 33 + kl];
            #pragma unroll
            for (int i = 0; i < 4; ++i)
                #pragma unroll
                for (int j = 0; j < 8; ++j) acc[i][j] += av[i] * wv[j];
        }
    }
    #pragma unroll
    for (int i = 0; i < 4; ++i) {
        int row = row0 + r0 + i;
        if (row < n) {
            *(float4*)(out + (size_t)row * 128 + c0) =
                make_float4(acc[i][0], acc[i][1], acc[i][2], acc[i][3]);
            *(float4*)(out + (size_t)row * 128 + c0 + 4) =
                make_float4(acc[i][4], acc[i][5], acc[i][6], acc[i][7]);
        }
    }
}

// out[n][10] = A[n][128] @ W[128][10]
__global__ void k_gemm10(const float* __restrict__ A, const float* __restrict__ W,
                         float* __restrict__ out, int n) {
    __shared__ float Ws[FD * OUTD];
    int tid = threadIdx.x;
    for (int i = tid; i < FD * OUTD; i += blockDim.x) Ws[i] = W[i];
    __syncthreads();
    int i = blockIdx.x * blockDim.x + tid;
    if (i >= n) return;
    float acc[OUTD];
    #pragma unroll
    for (int c = 0; c < OUTD; ++c) acc[c] = 0.0f;
    const float* a = A + (size_t)i * FD;
    for (int k = 0; k < FD; ++k) {
        float av = a[k];
        #pragma unroll
        for (int c = 0; c < OUTD; ++c) acc[c] += av * Ws[k * OUTD + c];
    }
    float* o = out + (size_t)i * OUTD;
    #pragma unroll
    for (int c = 0; c < OUTD; ++c) o[c] = acc[c];
}

// ---------------- sparse aggregation (CSR by dst, gather form) ----------------

// one wave per node, 2 features/lane
__global__ __launch_bounds__(256) void k_spmm128(const int* __restrict__ rowptr,
        const int* __restrict__ col, const float* __restrict__ val,
        const float* __restrict__ tin, const float* __restrict__ bias,
        float* __restrict__ out, int n, int dorelu) {
    int w = (blockIdx.x * blockDim.x + threadIdx.x) >> 6;
    int lane = threadIdx.x & 63;
    if (w >= n) return;
    int beg = rowptr[w], end = rowptr[w + 1];
    float a0 = 0.0f, a1 = 0.0f;
    for (int e = beg; e < end; ++e) {
        int c = col[e];            // wave-uniform -> broadcast load
        float v = val[e];
        float2 t2 = *(const float2*)(tin + (size_t)c * FD + lane * 2);
        a0 += v * t2.x;
        a1 += v * t2.y;
    }
    a0 += bias[lane * 2];
    a1 += bias[lane * 2 + 1];
    if (dorelu) { a0 = fmaxf(a0, 0.0f); a1 = fmaxf(a1, 0.0f); }
    *(float2*)(out + (size_t)w * FD + lane * 2) = make_float2(a0, a1);
}

// one thread per (node, feature), 10 features
__global__ void k_spmm10(const int* __restrict__ rowptr, const int* __restrict__ col,
        const float* __restrict__ val, const float* __restrict__ tin,
        const float* __restrict__ bias, float* __restrict__ out, int n) {
    int t = blockIdx.x * blockDim.x + threadIdx.x;
    int node = t / OUTD;
    int c = t - node * OUTD;
    if (node >= n) return;
    int beg = rowptr[node], end = rowptr[node + 1];
    float acc = 0.0f;
    for (int e = beg; e < end; ++e)
        acc += val[e] * tin[(size_t)col[e] * OUTD + c];
    out[(size_t)node * OUTD + c] = acc + bias[c];
}

// ---------------- pooling + log_softmax ----------------

__global__ void k_pool(const float* __restrict__ h, const int* __restrict__ batch,
                       float* sums, float* cntg, int n) {
    int i = blockIdx.x * blockDim.x + threadIdx.x;
    if (i >= n) return;
    int b = batch[i];
    atomicAdd(&cntg[b], 1.0f);
    #pragma unroll
    for (int c = 0; c < OUTD; ++c)
        atomicAdd(&sums[b * OUTD + c], h[(size_t)i * OUTD + c]);
}

__global__ void k_finalize(const float* __restrict__ sums, const float* __restrict__ cntg,
                           float* __restrict__ out) {
    int g = threadIdx.x;
    if (g >= GG) return;
    float cf = fmaxf(cntg[g], 1.0f);
    float v[OUTD];
    float m = -1e30f;
    #pragma unroll
    for (int c = 0; c < OUTD; ++c) {
        v[c] = sums[g * OUTD + c] / cf;
        m = fmaxf(m, v[c]);
    }
    float s = 0.0f;
    #pragma unroll
    for (int c = 0; c < OUTD; ++c) s += expf(v[c] - m);
    float l = logf(s);
    #pragma unroll
    for (int c = 0; c < OUTD; ++c) out[g * OUTD + c] = v[c] - m - l;
}

// ---------------- launcher ----------------

extern "C" void kernel_launch(void* const* d_in, const int* in_sizes, int n_in,
                              void* d_out, int out_size, void* d_ws, size_t ws_size,
                              hipStream_t stream) {
    const float* x   = (const float*)d_in[0];
    const int*   ei  = (const int*)d_in[1];
    const float* ew  = (const float*)d_in[2];
    const int*   bat = (const int*)d_in[3];
    const float* W1  = (const float*)d_in[4];
    const float* b1  = (const float*)d_in[5];
    const float* W2  = (const float*)d_in[6];
    const float* b2  = (const float*)d_in[7];
    const float* W3  = (const float*)d_in[8];
    const float* b3  = (const float*)d_in[9];
    float* out = (float*)d_out;

    const int* src = ei;        // edge_index[0]
    const int* dst = ei + EE;   // edge_index[1]

    // workspace carve-up (256B aligned)
    char* p = (char*)d_ws;
    auto alloc = [&](size_t bytes) -> void* {
        void* r = (void*)p;
        p += (bytes + 255) & ~(size_t)255;
        return r;
    };
    float* deg    = (float*)alloc((size_t)NN * 4);         // becomes dinv in-place
    int*   cnt    = (int*)  alloc((size_t)NN * 4);
    int*   rowptr = (int*)  alloc((size_t)(NN + 1) * 4);
    int*   fill   = (int*)  alloc((size_t)NN * 4);
    int*   col    = (int*)  alloc((size_t)(EE + NN) * 4);
    float* val    = (float*)alloc((size_t)(EE + NN) * 4);
    float* bufA   = (float*)alloc((size_t)NN * FD * 4);
    float* bufB   = (float*)alloc((size_t)NN * FD * 4);
    float* bufC   = (float*)alloc((size_t)NN * OUTD * 4);
    float* bufD   = (float*)alloc((size_t)NN * OUTD * 4);
    float* sums   = (float*)alloc((size_t)GG * OUTD * 4);
    float* cntg   = (float*)alloc((size_t)GG * 4);
    (void)ws_size; (void)in_sizes; (void)n_in; (void)out_size;

    const int B = 256;
    // preprocessing: degree -> dinv -> CSR
    k_init  <<<(NN + B - 1) / B, B, 0, stream>>>(deg, cnt, sums, cntg, NN);
    k_degree<<<(EE + B - 1) / B, B, 0, stream>>>(dst, ew, deg, cnt, EE);
    k_dinv  <<<(NN + B - 1) / B, B, 0, stream>>>(deg, NN);
    k_scan  <<<1, 1024, 0, stream>>>(cnt, rowptr, fill, NN);
    k_fill  <<<(EE + NN + B - 1) / B, B, 0, stream>>>(src, dst, ew, deg, fill, col, val, EE, NN);

    // layer 1
    k_gemm128<<<(NN + 63) / 64, B, 0, stream>>>(x, W1, bufA, NN);
    k_spmm128<<<(NN * 64 + B - 1) / B, B, 0, stream>>>(rowptr, col, val, bufA, b1, bufB, NN, 1);
    // layer 2
    k_gemm128<<<(NN + 63) / 64, B, 0, stream>>>(bufB, W2, bufA, NN);
    k_spmm128<<<(NN * 64 + B - 1) / B, B, 0, stream>>>(rowptr, col, val, bufA, b2, bufB, NN, 1);
    // layer 3
    k_gemm10 <<<(NN + B - 1) / B, B, 0, stream>>>(bufB, W3, bufC, NN);
    k_spmm10 <<<(NN * OUTD + B - 1) / B, B, 0, stream>>>(rowptr, col, val, bufC, b3, bufD, NN);
    // pool + log_softmax
    k_pool    <<<(NN + B - 1) / B, B, 0, stream>>>(bufD, bat, sums, cntg, NN);
    k_finalize<<<1, 64, 0, stream>>>(sums, cntg, out);
}

// Round 2
// 588.113 us; speedup vs baseline: 1.7012x; 1.7012x over previous
//
#include <hip/hip_runtime.h>
#include <math.h>

#define NN 50000
#define EE 800000
#define GG 64
#define FD 128
#define OUTD 10

// ---------------- preprocessing ----------------

__global__ void k_init(float* deg, int* cnt, int n) {
    int i = blockIdx.x * blockDim.x + threadIdx.x;
    if (i < n) { deg[i] = 1.0f; cnt[i] = 1; }   // self-loop weight 1, self-loop count 1
}

__global__ void k_degree(const int* __restrict__ dst, const float* __restrict__ w,
                         float* deg, int* cnt, int e) {
    int i = blockIdx.x * blockDim.x + threadIdx.x;
    if (i >= e) return;
    int d = dst[i];
    atomicAdd(&deg[d], w[i]);
    atomicAdd(&cnt[d], 1);
}

__global__ void k_dinv(float* deg, int n) {
    int i = blockIdx.x * blockDim.x + threadIdx.x;
    if (i >= n) return;
    deg[i] = 1.0f / sqrtf(deg[i]);   // deg >= 1 always (self-loop)
}

// single-block exclusive scan of cnt[0..n) -> rowptr, plus copy to fill, rowptr[n]=total
__global__ void k_scan(const int* __restrict__ cnt, int* __restrict__ rowptr,
                       int* __restrict__ fill, int n) {
    __shared__ int wtot[16];
    __shared__ int carry_s;
    int tid = threadIdx.x;
    int lane = tid & 63, wv = tid >> 6;
    if (tid == 0) carry_s = 0;
    __syncthreads();
    for (int base = 0; base < n; base += 1024) {
        int i = base + tid;
        int v = (i < n) ? cnt[i] : 0;
        int s = v;
        #pragma unroll
        for (int off = 1; off < 64; off <<= 1) {
            int u = __shfl_up(s, off, 64);
            if (lane >= off) s += u;
        }
        if (lane == 63) wtot[wv] = s;
        __syncthreads();
        int carry_local = carry_s;
        int wpre = 0;
        for (int j = 0; j < wv; ++j) wpre += wtot[j];
        int excl = carry_local + wpre + (s - v);
        if (i < n) { rowptr[i] = excl; fill[i] = excl; }
        __syncthreads();
        if (tid == 1023) carry_s = excl + v;   // inclusive of last element = new carry
        __syncthreads();
    }
    if (tid == 0) rowptr[n] = carry_s;
}

__global__ void k_fill(const int* __restrict__ src, const int* __restrict__ dst,
                       const float* __restrict__ w, const float* __restrict__ dinv,
                       int* fill, int* __restrict__ col, float* __restrict__ val,
                       int e, int n) {
    int i = blockIdx.x * blockDim.x + threadIdx.x;
    if (i < e) {
        int s = src[i], d = dst[i];
        int pos = atomicAdd(&fill[d], 1);
        col[pos] = s;
        val[pos] = dinv[s] * w[i] * dinv[d];
    } else if (i < e + n) {
        int nd = i - e;
        int pos = atomicAdd(&fill[nd], 1);
        col[pos] = nd;
        val[pos] = dinv[nd] * dinv[nd];
    }
}

// batch is sorted: find graph segment starts. gstart[g] = first node with batch>=g.
__global__ void k_bounds(const int* __restrict__ batch, int* __restrict__ gstart, int n) {
    int i = blockIdx.x * blockDim.x + threadIdx.x;
    if (i >= n) return;
    int b = batch[i];
    int bp = (i == 0) ? -1 : batch[i - 1];
    for (int g = bp + 1; g <= b; ++g) gstart[g] = i;
    if (i == n - 1)
        for (int g = b + 1; g <= GG; ++g) gstart[g] = n;
}

// ---------------- dense transforms ----------------

// out[n][128] = A[n][128] @ W[128][128], f32. 64-row tile per block, 256 threads,
// per-thread 4 rows x 8 cols. k staged in chunks of 32.
__global__ __launch_bounds__(256) void k_gemm128(const float* __restrict__ A,
        const float* __restrict__ W, float* __restrict__ out, int n) {
    __shared__ float Ws[32 * 128];
    __shared__ float As[64 * 33];   // +1 pad: 2-way max bank aliasing (free)
    int tid = threadIdx.x;
    int row0 = blockIdx.x * 64;
    int rg = tid & 15, cg = tid >> 4;
    int r0 = rg * 4, c0 = cg * 8;
    float acc[4][8];
    #pragma unroll
    for (int i = 0; i < 4; ++i)
        #pragma unroll
        for (int j = 0; j < 8; ++j) acc[i][j] = 0.0f;

    for (int kk = 0; kk < 128; kk += 32) {
        __syncthreads();
        for (int i = tid; i < 32 * 128 / 4; i += 256)
            ((float4*)Ws)[i] = ((const float4*)(W + kk * 128))[i];
        for (int j = tid; j < 64 * 32; j += 256) {
            int r = j >> 5, kl = j & 31;
            float v = 0.0f;
            int row = row0 + r;
            if (row < n) v = A[(size_t)row * 128 + kk + kl];
            As[r * 33 + kl] = v;
        }
        __syncthreads();
        #pragma unroll
        for (int kl = 0; kl < 32; ++kl) {
            float wv[8];
            *(float4*)&wv[0] = *(const float4*)&Ws[kl * 128 + c0];
            *(float4*)&wv[4] = *(const float4*)&Ws[kl * 128 + c0 + 4];
            float av[4];
            #pragma unroll
            for (int i = 0; i < 4; ++i) av[i] = As[(r0 + i) * 33 + kl];
            #pragma unroll
            for (int i = 0; i < 4; ++i)
                #pragma unroll
                for (int j = 0; j < 8; ++j) acc[i][j] += av[i] * wv[j];
        }
    }
    #pragma unroll
    for (int i = 0; i < 4; ++i) {
        int row = row0 + r0 + i;
        if (row < n) {
            *(float4*)(out + (size_t)row * 128 + c0) =
                make_float4(acc[i][0], acc[i][1], acc[i][2], acc[i][3]);
            *(float4*)(out + (size_t)row * 128 + c0 + 4) =
                make_float4(acc[i][4], acc[i][5], acc[i][6], acc[i][7]);
        }
    }
}

// out[n][10] = A[n][128] @ W[128][10]
__global__ void k_gemm10(const float* __restrict__ A, const float* __restrict__ W,
                         float* __restrict__ out, int n) {
    __shared__ float Ws[FD * OUTD];
    int tid = threadIdx.x;
    for (int i = tid; i < FD * OUTD; i += blockDim.x) Ws[i] = W[i];
    __syncthreads();
    int i = blockIdx.x * blockDim.x + tid;
    if (i >= n) return;
    float acc[OUTD];
    #pragma unroll
    for (int c = 0; c < OUTD; ++c) acc[c] = 0.0f;
    const float* a = A + (size_t)i * FD;
    for (int k = 0; k < FD; ++k) {
        float av = a[k];
        #pragma unroll
        for (int c = 0; c < OUTD; ++c) acc[c] += av * Ws[k * OUTD + c];
    }
    float* o = out + (size_t)i * OUTD;
    #pragma unroll
    for (int c = 0; c < OUTD; ++c) o[c] = acc[c];
}

// ---------------- sparse aggregation (CSR by dst, gather form) ----------------

// one wave per node, 2 features/lane
__global__ __launch_bounds__(256) void k_spmm128(const int* __restrict__ rowptr,
        const int* __restrict__ col, const float* __restrict__ val,
        const float* __restrict__ tin, const float* __restrict__ bias,
        float* __restrict__ out, int n, int dorelu) {
    int w = (blockIdx.x * blockDim.x + threadIdx.x) >> 6;
    int lane = threadIdx.x & 63;
    if (w >= n) return;
    int beg = rowptr[w], end = rowptr[w + 1];
    float a0 = 0.0f, a1 = 0.0f;
    for (int e = beg; e < end; ++e) {
        int c = col[e];            // wave-uniform -> broadcast load
        float v = val[e];
        float2 t2 = *(const float2*)(tin + (size_t)c * FD + lane * 2);
        a0 += v * t2.x;
        a1 += v * t2.y;
    }
    a0 += bias[lane * 2];
    a1 += bias[lane * 2 + 1];
    if (dorelu) { a0 = fmaxf(a0, 0.0f); a1 = fmaxf(a1, 0.0f); }
    *(float2*)(out + (size_t)w * FD + lane * 2) = make_float2(a0, a1);
}

// one thread per (node, feature), 10 features
__global__ void k_spmm10(const int* __restrict__ rowptr, const int* __restrict__ col,
        const float* __restrict__ val, const float* __restrict__ tin,
        const float* __restrict__ bias, float* __restrict__ out, int n) {
    int t = blockIdx.x * blockDim.x + threadIdx.x;
    int node = t / OUTD;
    int c = t - node * OUTD;
    if (node >= n) return;
    int beg = rowptr[node], end = rowptr[node + 1];
    float acc = 0.0f;
    for (int e = beg; e < end; ++e)
        acc += val[e] * tin[(size_t)col[e] * OUTD + c];
    out[(size_t)node * OUTD + c] = acc + bias[c];
}

// ---------------- pooling + log_softmax (contention-free, 1 block/graph) ----------------

__global__ __launch_bounds__(256) void k_poolfin(const float* __restrict__ h,
        const int* __restrict__ gstart, float* __restrict__ out) {
    int g = blockIdx.x;
    int beg = gstart[g], end = gstart[g + 1];
    int tid = threadIdx.x;
    int lane = tid & 63, wv = tid >> 6;
    float acc[OUTD];
    #pragma unroll
    for (int c = 0; c < OUTD; ++c) acc[c] = 0.0f;
    for (int i = beg + tid; i < end; i += 256) {
        const float* hp = h + (size_t)i * OUTD;
        #pragma unroll
        for (int c = 0; c < OUTD; ++c) acc[c] += hp[c];
    }
    // wave reduce
    #pragma unroll
    for (int off = 32; off >= 1; off >>= 1)
        #pragma unroll
        for (int c = 0; c < OUTD; ++c) acc[c] += __shfl_down(acc[c], off, 64);
    __shared__ float ws[4][OUTD];
    if (lane == 0)
        #pragma unroll
        for (int c = 0; c < OUTD; ++c) ws[wv][c] = acc[c];
    __syncthreads();
    if (tid == 0) {
        float cf = fmaxf((float)(end - beg), 1.0f);
        float v[OUTD], m = -1e30f;
        #pragma unroll
        for (int c = 0; c < OUTD; ++c) {
            v[c] = (ws[0][c] + ws[1][c] + ws[2][c] + ws[3][c]) / cf;
            m = fmaxf(m, v[c]);
        }
        float s = 0.0f;
        #pragma unroll
        for (int c = 0; c < OUTD; ++c) s += expf(v[c] - m);
        float l = logf(s);
        #pragma unroll
        for (int c = 0; c < OUTD; ++c) out[g * OUTD + c] = v[c] - m - l;
    }
}

// ---------------- launcher ----------------

extern "C" void kernel_launch(void* const* d_in, const int* in_sizes, int n_in,
                              void* d_out, int out_size, void* d_ws, size_t ws_size,
                              hipStream_t stream) {
    const float* x   = (const float*)d_in[0];
    const int*   ei  = (const int*)d_in[1];
    const float* ew  = (const float*)d_in[2];
    const int*   bat = (const int*)d_in[3];
    const float* W1  = (const float*)d_in[4];
    const float* b1  = (const float*)d_in[5];
    const float* W2  = (const float*)d_in[6];
    const float* b2  = (const float*)d_in[7];
    const float* W3  = (const float*)d_in[8];
    const float* b3  = (const float*)d_in[9];
    float* out = (float*)d_out;

    const int* src = ei;        // edge_index[0]
    const int* dst = ei + EE;   // edge_index[1]

    char* p = (char*)d_ws;
    auto alloc = [&](size_t bytes) -> void* {
        void* r = (void*)p;
        p += (bytes + 255) & ~(size_t)255;
        return r;
    };
    float* deg    = (float*)alloc((size_t)NN * 4);         // becomes dinv in-place
    int*   cnt    = (int*)  alloc((size_t)NN * 4);
    int*   rowptr = (int*)  alloc((size_t)(NN + 1) * 4);
    int*   fill   = (int*)  alloc((size_t)NN * 4);
    int*   col    = (int*)  alloc((size_t)(EE + NN) * 4);
    float* val    = (float*)alloc((size_t)(EE + NN) * 4);
    float* bufA   = (float*)alloc((size_t)NN * FD * 4);
    float* bufB   = (float*)alloc((size_t)NN * FD * 4);
    float* bufC   = (float*)alloc((size_t)NN * OUTD * 4);
    float* bufD   = (float*)alloc((size_t)NN * OUTD * 4);
    int*   gstart = (int*)  alloc((size_t)(GG + 1) * 4);
    (void)ws_size; (void)in_sizes; (void)n_in; (void)out_size;

    const int B = 256;
    // preprocessing: degree -> dinv -> CSR -> graph bounds
    k_init  <<<(NN + B - 1) / B, B, 0, stream>>>(deg, cnt, NN);
    k_degree<<<(EE + B - 1) / B, B, 0, stream>>>(dst, ew, deg, cnt, EE);
    k_dinv  <<<(NN + B - 1) / B, B, 0, stream>>>(deg, NN);
    k_scan  <<<1, 1024, 0, stream>>>(cnt, rowptr, fill, NN);
    k_fill  <<<(EE + NN + B - 1) / B, B, 0, stream>>>(src, dst, ew, deg, fill, col, val, EE, NN);
    k_bounds<<<(NN + B - 1) / B, B, 0, stream>>>(bat, gstart, NN);

    // layer 1
    k_gemm128<<<(NN + 63) / 64, B, 0, stream>>>(x, W1, bufA, NN);
    k_spmm128<<<(NN * 64 + B - 1) / B, B, 0, stream>>>(rowptr, col, val, bufA, b1, bufB, NN, 1);
    // layer 2
    k_gemm128<<<(NN + 63) / 64, B, 0, stream>>>(bufB, W2, bufA, NN);
    k_spmm128<<<(NN * 64 + B - 1) / B, B, 0, stream>>>(rowptr, col, val, bufA, b2, bufB, NN, 1);
    // layer 3
    k_gemm10 <<<(NN + B - 1) / B, B, 0, stream>>>(bufB, W3, bufC, NN);
    k_spmm10 <<<(NN * OUTD + B - 1) / B, B, 0, stream>>>(rowptr, col, val, bufC, b3, bufD, NN);
    // pool + log_softmax
    k_poolfin<<<GG, 256, 0, stream>>>(bufD, gstart, out);
}

// Round 3
// 376.661 us; speedup vs baseline: 2.6563x; 1.5614x over previous
//
#include <hip/hip_runtime.h>
#include <math.h>

#define NN 50000
#define EE 800000
#define GG 64
#define FD 128
#define OUTD 10
#define NB 49           // ceil(NN/1024) scan blocks

typedef __attribute__((ext_vector_type(8))) short s8v;    // 8 bf16
typedef __attribute__((ext_vector_type(4))) float f4v;    // 4 f32 acc

static __device__ inline unsigned short f2b(float f) {    // f32 -> bf16 RNE
    unsigned int u = __float_as_uint(f);
    return (unsigned short)((u + 0x7FFFu + ((u >> 16) & 1u)) >> 16);
}

// ---------------- preprocessing ----------------

__global__ void k_init(float* deg, int* cnt, int n) {
    int i = blockIdx.x * blockDim.x + threadIdx.x;
    if (i < n) { deg[i] = 1.0f; cnt[i] = 1; }   // self-loop weight 1, count 1
}

__global__ void k_degree(const int* __restrict__ dst, const float* __restrict__ w,
                         float* deg, int* cnt, int e) {
    int i = blockIdx.x * blockDim.x + threadIdx.x;
    if (i >= e) return;
    int d = dst[i];
    atomicAdd(&deg[d], w[i]);
    atomicAdd(&cnt[d], 1);
}

__global__ void k_dinv(float* deg, int n) {
    int i = blockIdx.x * blockDim.x + threadIdx.x;
    if (i >= n) return;
    deg[i] = 1.0f / sqrtf(deg[i]);
}

// three-kernel scan: per-block scan -> scan of block sums -> add offsets
__global__ __launch_bounds__(1024) void k_scanA(const int* __restrict__ cnt,
        int* __restrict__ rowptr, int* __restrict__ blocksum, int n) {
    __shared__ int wtot[16];
    int tid = threadIdx.x;
    int i = blockIdx.x * 1024 + tid;
    int lane = tid & 63, wv = tid >> 6;
    int v = (i < n) ? cnt[i] : 0;
    int s = v;
    #pragma unroll
    for (int off = 1; off < 64; off <<= 1) {
        int u = __shfl_up(s, off, 64);
        if (lane >= off) s += u;
    }
    if (lane == 63) wtot[wv] = s;
    __syncthreads();
    int wpre = 0;
    for (int j = 0; j < wv; ++j) wpre += wtot[j];
    if (i < n) rowptr[i] = wpre + s - v;          // block-local exclusive
    if (tid == 1023) blocksum[blockIdx.x] = wpre + s;
}

__global__ void k_scanB(int* blocksum, int* rowptr) {  // 1 block, 64 threads
    int l = threadIdx.x;
    int v = (l < NB) ? blocksum[l] : 0;
    int s = v;
    #pragma unroll
    for (int off = 1; off < 64; off <<= 1) {
        int u = __shfl_up(s, off, 64);
        if (l >= off) s += u;
    }
    if (l < NB) blocksum[l] = s - v;              // exclusive, in place
    if (l == NB - 1) rowptr[NN] = s;              // total
}

__global__ __launch_bounds__(1024) void k_scanC(int* __restrict__ rowptr,
        int* __restrict__ fill, const int* __restrict__ blocksum, int n) {
    int i = blockIdx.x * 1024 + threadIdx.x;
    if (i >= n) return;
    int r = rowptr[i] + blocksum[blockIdx.x];
    rowptr[i] = r;
    fill[i] = r;
}

__global__ void k_fill(const int* __restrict__ src, const int* __restrict__ dst,
                       const float* __restrict__ w, const float* __restrict__ dinv,
                       int* fill, int* __restrict__ col, float* __restrict__ val,
                       int e, int n) {
    int i = blockIdx.x * blockDim.x + threadIdx.x;
    if (i < e) {
        int s = src[i], d = dst[i];
        int pos = atomicAdd(&fill[d], 1);
        col[pos] = s;
        val[pos] = dinv[s] * w[i] * dinv[d];
    } else if (i < e + n) {
        int nd = i - e;
        int pos = atomicAdd(&fill[nd], 1);
        col[pos] = nd;
        val[pos] = dinv[nd] * dinv[nd];
    }
}

// batch is sorted: gstart[g] = first node with batch >= g
__global__ void k_bounds(const int* __restrict__ batch, int* __restrict__ gstart, int n) {
    int i = blockIdx.x * blockDim.x + threadIdx.x;
    if (i >= n) return;
    int b = batch[i];
    int bp = (i == 0) ? -1 : batch[i - 1];
    for (int g = bp + 1; g <= b; ++g) gstart[g] = i;
    if (i == n - 1)
        for (int g = b + 1; g <= GG; ++g) gstart[g] = n;
}

// ---------------- dtype conversion ----------------

// f32[n8*8] -> bf16, 8 elems/thread
__global__ void k_cvt(const float* __restrict__ in, unsigned short* __restrict__ out, int n8) {
    int i = blockIdx.x * blockDim.x + threadIdx.x;
    if (i >= n8) return;
    const float4* p = (const float4*)in + (size_t)i * 2;
    float4 a = p[0], b = p[1];
    uint4 r;
    r.x = (unsigned)f2b(a.x) | ((unsigned)f2b(a.y) << 16);
    r.y = (unsigned)f2b(a.z) | ((unsigned)f2b(a.w) << 16);
    r.z = (unsigned)f2b(b.x) | ((unsigned)f2b(b.y) << 16);
    r.w = (unsigned)f2b(b.z) | ((unsigned)f2b(b.w) << 16);
    *((uint4*)out + i) = r;
}

// W f32 [128k x 128n] -> Wt bf16 [128n x 128k]
__global__ void k_w128t(const float* __restrict__ W, unsigned short* __restrict__ Wt) {
    int i = blockIdx.x * blockDim.x + threadIdx.x;   // i = n*128 + k
    if (i >= FD * FD) return;
    int nn = i >> 7, k = i & 127;
    Wt[i] = f2b(W[k * FD + nn]);
}

// ---------------- dense transform: bf16 MFMA GEMM ----------------
// out[n][128] = A[n][128] @ W[128][128], A bf16, Wt = W^T bf16, out bf16.
// block = 256 thr = 4 waves, 64 rows/block, 16 rows/wave, full 128 cols/wave.
__global__ __launch_bounds__(256) void k_gemm_bf(const unsigned short* __restrict__ A,
        const unsigned short* __restrict__ Wt, unsigned short* __restrict__ out, int n) {
    int tid = threadIdx.x;
    int wave = tid >> 6, lane = tid & 63;
    int quad = lane >> 4, c16 = lane & 15;
    int rowbase = blockIdx.x * 64 + wave * 16;
    int rowA = rowbase + c16;
    if (rowA >= n) rowA = n - 1;                  // clamp loads; stores guarded
    f4v acc[8];
    #pragma unroll
    for (int t = 0; t < 8; ++t) acc[t] = (f4v){0.f, 0.f, 0.f, 0.f};

    #pragma unroll
    for (int k0 = 0; k0 < 128; k0 += 32) {
        // A-frag: A[m=lane&15][k=quad*8+j] -> contiguous 8 bf16
        s8v a = *(const s8v*)(A + (size_t)rowA * FD + k0 + quad * 8);
        #pragma unroll
        for (int t = 0; t < 8; ++t) {
            // B-frag: B[k][n], n=lane&15, k=quad*8+j; Wt[n][k] row-major
            s8v b = *(const s8v*)(Wt + (size_t)(t * 16 + c16) * FD + k0 + quad * 8);
            acc[t] = __builtin_amdgcn_mfma_f32_16x16x32_bf16(a, b, acc[t], 0, 0, 0);
        }
    }
    // C/D: col = lane&15, row = quad*4 + reg
    #pragma unroll
    for (int t = 0; t < 8; ++t) {
        #pragma unroll
        for (int r = 0; r < 4; ++r) {
            int row = rowbase + quad * 4 + r;
            if (row < n) out[(size_t)row * FD + t * 16 + c16] = f2b(acc[t][r]);
        }
    }
}

// out[n][10] = A[n][128] @ W[128][10], A bf16, W f32 (in LDS), out f32
__global__ void k_gemm10(const unsigned short* __restrict__ A, const float* __restrict__ W,
                         float* __restrict__ out, int n) {
    __shared__ float Ws[FD * OUTD];
    int tid = threadIdx.x;
    for (int i = tid; i < FD * OUTD; i += blockDim.x) Ws[i] = W[i];
    __syncthreads();
    int i = blockIdx.x * blockDim.x + tid;
    if (i >= n) return;
    float acc[OUTD];
    #pragma unroll
    for (int c = 0; c < OUTD; ++c) acc[c] = 0.0f;
    const unsigned short* a = A + (size_t)i * FD;
    for (int k0 = 0; k0 < FD; k0 += 8) {
        uint4 t = *(const uint4*)(a + k0);
        float av[8];
        av[0] = __uint_as_float(t.x << 16); av[1] = __uint_as_float(t.x & 0xFFFF0000u);
        av[2] = __uint_as_float(t.y << 16); av[3] = __uint_as_float(t.y & 0xFFFF0000u);
        av[4] = __uint_as_float(t.z << 16); av[5] = __uint_as_float(t.z & 0xFFFF0000u);
        av[6] = __uint_as_float(t.w << 16); av[7] = __uint_as_float(t.w & 0xFFFF0000u);
        #pragma unroll
        for (int j = 0; j < 8; ++j)
            #pragma unroll
            for (int c = 0; c < OUTD; ++c) acc[c] += av[j] * Ws[(k0 + j) * OUTD + c];
    }
    float* o = out + (size_t)i * OUTD;
    #pragma unroll
    for (int c = 0; c < OUTD; ++c) o[c] = acc[c];
}

// ---------------- sparse aggregation, bf16 features ----------------
// one wave per node; 4 edges/iter (16 lanes x 16B each); f32 accum; bf16 out
__global__ __launch_bounds__(256) void k_spmm_bf(const int* __restrict__ rowptr,
        const int* __restrict__ col, const float* __restrict__ val,
        const unsigned short* __restrict__ tin, const float* __restrict__ bias,
        unsigned short* __restrict__ out, int n, int dorelu) {
    int w = (blockIdx.x * blockDim.x + threadIdx.x) >> 6;
    int lane = threadIdx.x & 63;
    if (w >= n) return;
    int c = lane & 15, g = lane >> 4;
    int beg = rowptr[w], end = rowptr[w + 1];
    float acc[8];
    #pragma unroll
    for (int j = 0; j < 8; ++j) acc[j] = 0.0f;
    for (int e0 = beg; e0 < end; e0 += 4) {
        int e = e0 + g;
        bool ok = e < end;
        int ci = ok ? col[e] : 0;
        float v = ok ? val[e] : 0.0f;
        uint4 t = *(const uint4*)(tin + (size_t)ci * FD + c * 8);
        acc[0] += v * __uint_as_float(t.x << 16);
        acc[1] += v * __uint_as_float(t.x & 0xFFFF0000u);
        acc[2] += v * __uint_as_float(t.y << 16);
        acc[3] += v * __uint_as_float(t.y & 0xFFFF0000u);
        acc[4] += v * __uint_as_float(t.z << 16);
        acc[5] += v * __uint_as_float(t.z & 0xFFFF0000u);
        acc[6] += v * __uint_as_float(t.w << 16);
        acc[7] += v * __uint_as_float(t.w & 0xFFFF0000u);
    }
    // reduce across the 4 edge-groups (xor lane bits 4,5)
    #pragma unroll
    for (int j = 0; j < 8; ++j) {
        acc[j] += __shfl_xor(acc[j], 16, 64);
        acc[j] += __shfl_xor(acc[j], 32, 64);
    }
    if (g == 0) {
        uint4 r;
        float o[8];
        #pragma unroll
        for (int j = 0; j < 8; ++j) {
            float x = acc[j] + bias[c * 8 + j];
            o[j] = dorelu ? fmaxf(x, 0.0f) : x;
        }
        r.x = (unsigned)f2b(o[0]) | ((unsigned)f2b(o[1]) << 16);
        r.y = (unsigned)f2b(o[2]) | ((unsigned)f2b(o[3]) << 16);
        r.z = (unsigned)f2b(o[4]) | ((unsigned)f2b(o[5]) << 16);
        r.w = (unsigned)f2b(o[6]) | ((unsigned)f2b(o[7]) << 16);
        *(uint4*)(out + (size_t)w * FD + c * 8) = r;
    }
}

// one thread per (node, feature), 10 features, f32
__global__ void k_spmm10(const int* __restrict__ rowptr, const int* __restrict__ col,
        const float* __restrict__ val, const float* __restrict__ tin,
        const float* __restrict__ bias, float* __restrict__ out, int n) {
    int t = blockIdx.x * blockDim.x + threadIdx.x;
    int node = t / OUTD;
    int c = t - node * OUTD;
    if (node >= n) return;
    int beg = rowptr[node], end = rowptr[node + 1];
    float acc = 0.0f;
    for (int e = beg; e < end; ++e)
        acc += val[e] * tin[(size_t)col[e] * OUTD + c];
    out[(size_t)node * OUTD + c] = acc + bias[c];
}

// ---------------- pooling + log_softmax (1 block/graph) ----------------

__global__ __launch_bounds__(256) void k_poolfin(const float* __restrict__ h,
        const int* __restrict__ gstart, float* __restrict__ out) {
    int g = blockIdx.x;
    int beg = gstart[g], end = gstart[g + 1];
    int tid = threadIdx.x;
    int lane = tid & 63, wv = tid >> 6;
    float acc[OUTD];
    #pragma unroll
    for (int c = 0; c < OUTD; ++c) acc[c] = 0.0f;
    for (int i = beg + tid; i < end; i += 256) {
        const float* hp = h + (size_t)i * OUTD;
        #pragma unroll
        for (int c = 0; c < OUTD; ++c) acc[c] += hp[c];
    }
    #pragma unroll
    for (int off = 32; off >= 1; off >>= 1)
        #pragma unroll
        for (int c = 0; c < OUTD; ++c) acc[c] += __shfl_down(acc[c], off, 64);
    __shared__ float ws[4][OUTD];
    if (lane == 0)
        #pragma unroll
        for (int c = 0; c < OUTD; ++c) ws[wv][c] = acc[c];
    __syncthreads();
    if (tid == 0) {
        float cf = fmaxf((float)(end - beg), 1.0f);
        float v[OUTD], m = -1e30f;
        #pragma unroll
        for (int c = 0; c < OUTD; ++c) {
            v[c] = (ws[0][c] + ws[1][c] + ws[2][c] + ws[3][c]) / cf;
            m = fmaxf(m, v[c]);
        }
        float s = 0.0f;
        #pragma unroll
        for (int c = 0; c < OUTD; ++c) s += expf(v[c] - m);
        float l = logf(s);
        #pragma unroll
        for (int c = 0; c < OUTD; ++c) out[g * OUTD + c] = v[c] - m - l;
    }
}

// ---------------- launcher ----------------

extern "C" void kernel_launch(void* const* d_in, const int* in_sizes, int n_in,
                              void* d_out, int out_size, void* d_ws, size_t ws_size,
                              hipStream_t stream) {
    const float* x   = (const float*)d_in[0];
    const int*   ei  = (const int*)d_in[1];
    const float* ew  = (const float*)d_in[2];
    const int*   bat = (const int*)d_in[3];
    const float* W1  = (const float*)d_in[4];
    const float* b1  = (const float*)d_in[5];
    const float* W2  = (const float*)d_in[6];
    const float* b2  = (const float*)d_in[7];
    const float* W3  = (const float*)d_in[8];
    const float* b3  = (const float*)d_in[9];
    float* out = (float*)d_out;

    const int* src = ei;
    const int* dst = ei + EE;

    char* p = (char*)d_ws;
    auto alloc = [&](size_t bytes) -> void* {
        void* r = (void*)p;
        p += (bytes + 255) & ~(size_t)255;
        return r;
    };
    float*          deg    = (float*)alloc((size_t)NN * 4);
    int*            cnt    = (int*)  alloc((size_t)NN * 4);
    int*            rowptr = (int*)  alloc((size_t)(NN + 1) * 4);
    int*            fill   = (int*)  alloc((size_t)NN * 4);
    int*            col    = (int*)  alloc((size_t)(EE + NN) * 4);
    float*          val    = (float*)alloc((size_t)(EE + NN) * 4);
    unsigned short* xbf    = (unsigned short*)alloc((size_t)NN * FD * 2);
    unsigned short* Wt1    = (unsigned short*)alloc((size_t)FD * FD * 2);
    unsigned short* Wt2    = (unsigned short*)alloc((size_t)FD * FD * 2);
    unsigned short* hA     = (unsigned short*)alloc((size_t)NN * FD * 2);
    unsigned short* hB     = (unsigned short*)alloc((size_t)NN * FD * 2);
    float*          bufC   = (float*)alloc((size_t)NN * OUTD * 4);
    float*          bufD   = (float*)alloc((size_t)NN * OUTD * 4);
    int*            bsum   = (int*)  alloc((size_t)(NB + 1) * 4);
    int*            gstart = (int*)  alloc((size_t)(GG + 1) * 4);
    (void)ws_size; (void)in_sizes; (void)n_in; (void)out_size;

    const int B = 256;
    // preprocessing
    k_init  <<<(NN + B - 1) / B, B, 0, stream>>>(deg, cnt, NN);
    k_degree<<<(EE + B - 1) / B, B, 0, stream>>>(dst, ew, deg, cnt, EE);
    k_dinv  <<<(NN + B - 1) / B, B, 0, stream>>>(deg, NN);
    k_scanA <<<NB, 1024, 0, stream>>>(cnt, rowptr, bsum, NN);
    k_scanB <<<1, 64, 0, stream>>>(bsum, rowptr);
    k_scanC <<<NB, 1024, 0, stream>>>(rowptr, fill, bsum, NN);
    k_fill  <<<(EE + NN + B - 1) / B, B, 0, stream>>>(src, dst, ew, deg, fill, col, val, EE, NN);
    k_bounds<<<(NN + B - 1) / B, B, 0, stream>>>(bat, gstart, NN);
    // dtype prep
    k_cvt   <<<(NN * FD / 8 + B - 1) / B, B, 0, stream>>>(x, xbf, NN * FD / 8);
    k_w128t <<<(FD * FD + B - 1) / B, B, 0, stream>>>(W1, Wt1);
    k_w128t <<<(FD * FD + B - 1) / B, B, 0, stream>>>(W2, Wt2);

    // layer 1
    k_gemm_bf<<<(NN + 63) / 64, B, 0, stream>>>(xbf, Wt1, hA, NN);
    k_spmm_bf<<<(NN * 64 + B - 1) / B, B, 0, stream>>>(rowptr, col, val, hA, b1, hB, NN, 1);
    // layer 2
    k_gemm_bf<<<(NN + 63) / 64, B, 0, stream>>>(hB, Wt2, hA, NN);
    k_spmm_bf<<<(NN * 64 + B - 1) / B, B, 0, stream>>>(rowptr, col, val, hA, b2, hB, NN, 1);
    // layer 3
    k_gemm10 <<<(NN + B - 1) / B, B, 0, stream>>>(hB, W3, bufC, NN);
    k_spmm10 <<<(NN * OUTD + B - 1) / B, B, 0, stream>>>(rowptr, col, val, bufC, b3, bufD, NN);
    // pool + log_softmax
    k_poolfin<<<GG, 256, 0, stream>>>(bufD, gstart, out);
}

// Round 4
// 343.205 us; speedup vs baseline: 2.9152x; 1.0975x over previous
//
#include <hip/hip_runtime.h>
#include <math.h>

#define NN 50000
#define EE 800000
#define GG 64
#define FD 128
#define OUTD 10
#define NB 49           // ceil(NN/1024) scan blocks

typedef __attribute__((ext_vector_type(8))) short s8v;    // 8 bf16
typedef __attribute__((ext_vector_type(4))) float f4v;    // 4 f32 acc

static __device__ inline unsigned short f2b(float f) {    // f32 -> bf16 RNE
    unsigned int u = __float_as_uint(f);
    return (unsigned short)((u + 0x7FFFu + ((u >> 16) & 1u)) >> 16);
}

// packed degree accumulator: bits [0,44) = sum(w) in 2^-32 fixed point,
// bits [44,64) = edge count. One u64 atomic per edge instead of two u32.
#define DEG_SCALE 4294967296.0
#define DEG_MASK  ((1ull << 44) - 1)

// ---------------- preprocessing ----------------

__global__ void k_init(unsigned long long* packed, int n) {
    int i = blockIdx.x * blockDim.x + threadIdx.x;
    if (i < n) packed[i] = (1ull << 44) | (1ull << 32);   // cnt=1, deg=1.0 (self-loop)
}

__global__ void k_degree(const int* __restrict__ dst, const float* __restrict__ w,
                         unsigned long long* packed, int e) {
    int i = blockIdx.x * blockDim.x + threadIdx.x;
    if (i >= e) return;
    unsigned long long q = (unsigned long long)((double)w[i] * DEG_SCALE + 0.5);
    atomicAdd(&packed[dst[i]], (1ull << 44) | q);
}

// unpack: cnt for scan, dinv = 1/sqrt(deg)
__global__ void k_dinv(const unsigned long long* __restrict__ packed,
                       int* __restrict__ cnt, float* __restrict__ dinv, int n) {
    int i = blockIdx.x * blockDim.x + threadIdx.x;
    if (i >= n) return;
    unsigned long long p = packed[i];
    cnt[i] = (int)(p >> 44);
    float deg = (float)((double)(p & DEG_MASK) * (1.0 / DEG_SCALE));
    dinv[i] = 1.0f / sqrtf(deg);
}

// three-kernel scan: per-block scan -> scan of block sums -> add offsets
__global__ __launch_bounds__(1024) void k_scanA(const int* __restrict__ cnt,
        int* __restrict__ rowptr, int* __restrict__ blocksum, int n) {
    __shared__ int wtot[16];
    int tid = threadIdx.x;
    int i = blockIdx.x * 1024 + tid;
    int lane = tid & 63, wv = tid >> 6;
    int v = (i < n) ? cnt[i] : 0;
    int s = v;
    #pragma unroll
    for (int off = 1; off < 64; off <<= 1) {
        int u = __shfl_up(s, off, 64);
        if (lane >= off) s += u;
    }
    if (lane == 63) wtot[wv] = s;
    __syncthreads();
    int wpre = 0;
    for (int j = 0; j < wv; ++j) wpre += wtot[j];
    if (i < n) rowptr[i] = wpre + s - v;          // block-local exclusive
    if (tid == 1023) blocksum[blockIdx.x] = wpre + s;
}

__global__ void k_scanB(int* blocksum, int* rowptr) {  // 1 block, 64 threads
    int l = threadIdx.x;
    int v = (l < NB) ? blocksum[l] : 0;
    int s = v;
    #pragma unroll
    for (int off = 1; off < 64; off <<= 1) {
        int u = __shfl_up(s, off, 64);
        if (l >= off) s += u;
    }
    if (l < NB) blocksum[l] = s - v;              // exclusive, in place
    if (l == NB - 1) rowptr[NN] = s;              // total
}

__global__ __launch_bounds__(1024) void k_scanC(int* __restrict__ rowptr,
        int* __restrict__ fill, const int* __restrict__ blocksum, int n) {
    int i = blockIdx.x * 1024 + threadIdx.x;
    if (i >= n) return;
    int r = rowptr[i] + blocksum[blockIdx.x];
    rowptr[i] = r;
    fill[i] = r;
}

// edges: packed (col, val) 8B store, one u32 atomic for position.
// edges occupy [rowptr[d], rowptr[d+1]-1); self-loop placed at rowptr[d+1]-1.
__global__ void k_fill(const int* __restrict__ src, const int* __restrict__ dst,
                       const float* __restrict__ w, const float* __restrict__ dinv,
                       int* fill, uint2* __restrict__ ent, int e) {
    int i = blockIdx.x * blockDim.x + threadIdx.x;
    if (i >= e) return;
    int s = src[i], d = dst[i];
    int pos = atomicAdd(&fill[d], 1);
    float v = dinv[s] * w[i] * dinv[d];
    ent[pos] = make_uint2((unsigned)s, __float_as_uint(v));
}

__global__ void k_selfloop(const int* __restrict__ rowptr, const float* __restrict__ dinv,
                           uint2* __restrict__ ent, int n) {
    int i = blockIdx.x * blockDim.x + threadIdx.x;
    if (i >= n) return;
    float di = dinv[i];
    ent[rowptr[i + 1] - 1] = make_uint2((unsigned)i, __float_as_uint(di * di));
}

// batch is sorted: gstart[g] = first node with batch >= g
__global__ void k_bounds(const int* __restrict__ batch, int* __restrict__ gstart, int n) {
    int i = blockIdx.x * blockDim.x + threadIdx.x;
    if (i >= n) return;
    int b = batch[i];
    int bp = (i == 0) ? -1 : batch[i - 1];
    for (int g = bp + 1; g <= b; ++g) gstart[g] = i;
    if (i == n - 1)
        for (int g = b + 1; g <= GG; ++g) gstart[g] = n;
}

// ---------------- dtype conversion ----------------

__global__ void k_cvt(const float* __restrict__ in, unsigned short* __restrict__ out, int n8) {
    int i = blockIdx.x * blockDim.x + threadIdx.x;
    if (i >= n8) return;
    const float4* p = (const float4*)in + (size_t)i * 2;
    float4 a = p[0], b = p[1];
    uint4 r;
    r.x = (unsigned)f2b(a.x) | ((unsigned)f2b(a.y) << 16);
    r.y = (unsigned)f2b(a.z) | ((unsigned)f2b(a.w) << 16);
    r.z = (unsigned)f2b(b.x) | ((unsigned)f2b(b.y) << 16);
    r.w = (unsigned)f2b(b.z) | ((unsigned)f2b(b.w) << 16);
    *((uint4*)out + i) = r;
}

// W f32 [128k x 128n] -> Wt bf16 [128n x 128k]
__global__ void k_w128t(const float* __restrict__ W, unsigned short* __restrict__ Wt) {
    int i = blockIdx.x * blockDim.x + threadIdx.x;   // i = n*128 + k
    if (i >= FD * FD) return;
    int nn = i >> 7, k = i & 127;
    Wt[i] = f2b(W[k * FD + nn]);
}

// ---------------- dense transform: bf16 MFMA GEMM ----------------
// out[n][128] = A[n][128] @ W[128][128]; 4 waves/block, 16 rows/wave.
__global__ __launch_bounds__(256) void k_gemm_bf(const unsigned short* __restrict__ A,
        const unsigned short* __restrict__ Wt, unsigned short* __restrict__ out, int n) {
    int tid = threadIdx.x;
    int wave = tid >> 6, lane = tid & 63;
    int quad = lane >> 4, c16 = lane & 15;
    int rowbase = blockIdx.x * 64 + wave * 16;
    int rowA = rowbase + c16;
    if (rowA >= n) rowA = n - 1;                  // clamp loads; stores guarded
    f4v acc[8];
    #pragma unroll
    for (int t = 0; t < 8; ++t) acc[t] = (f4v){0.f, 0.f, 0.f, 0.f};

    #pragma unroll
    for (int k0 = 0; k0 < 128; k0 += 32) {
        s8v a = *(const s8v*)(A + (size_t)rowA * FD + k0 + quad * 8);
        #pragma unroll
        for (int t = 0; t < 8; ++t) {
            s8v b = *(const s8v*)(Wt + (size_t)(t * 16 + c16) * FD + k0 + quad * 8);
            acc[t] = __builtin_amdgcn_mfma_f32_16x16x32_bf16(a, b, acc[t], 0, 0, 0);
        }
    }
    #pragma unroll
    for (int t = 0; t < 8; ++t) {
        #pragma unroll
        for (int r = 0; r < 4; ++r) {
            int row = rowbase + quad * 4 + r;
            if (row < n) out[(size_t)row * FD + t * 16 + c16] = f2b(acc[t][r]);
        }
    }
}

// out[n][10] = A[n][128] @ W[128][10], A bf16, W f32 (LDS), out f32
__global__ void k_gemm10(const unsigned short* __restrict__ A, const float* __restrict__ W,
                         float* __restrict__ out, int n) {
    __shared__ float Ws[FD * OUTD];
    int tid = threadIdx.x;
    for (int i = tid; i < FD * OUTD; i += blockDim.x) Ws[i] = W[i];
    __syncthreads();
    int i = blockIdx.x * blockDim.x + tid;
    if (i >= n) return;
    float acc[OUTD];
    #pragma unroll
    for (int c = 0; c < OUTD; ++c) acc[c] = 0.0f;
    const unsigned short* a = A + (size_t)i * FD;
    for (int k0 = 0; k0 < FD; k0 += 8) {
        uint4 t = *(const uint4*)(a + k0);
        float av[8];
        av[0] = __uint_as_float(t.x << 16); av[1] = __uint_as_float(t.x & 0xFFFF0000u);
        av[2] = __uint_as_float(t.y << 16); av[3] = __uint_as_float(t.y & 0xFFFF0000u);
        av[4] = __uint_as_float(t.z << 16); av[5] = __uint_as_float(t.z & 0xFFFF0000u);
        av[6] = __uint_as_float(t.w << 16); av[7] = __uint_as_float(t.w & 0xFFFF0000u);
        #pragma unroll
        for (int j = 0; j < 8; ++j)
            #pragma unroll
            for (int c = 0; c < OUTD; ++c) acc[c] += av[j] * Ws[(k0 + j) * OUTD + c];
    }
    float* o = out + (size_t)i * OUTD;
    #pragma unroll
    for (int c = 0; c < OUTD; ++c) o[c] = acc[c];
}

// ---------------- sparse aggregation, bf16 features ----------------
// one wave per node; 4 edges/iter (16 lanes x 16B each); f32 accum; bf16 out
__global__ __launch_bounds__(256) void k_spmm_bf(const int* __restrict__ rowptr,
        const uint2* __restrict__ ent, const unsigned short* __restrict__ tin,
        const float* __restrict__ bias, unsigned short* __restrict__ out,
        int n, int dorelu) {
    int w = (blockIdx.x * blockDim.x + threadIdx.x) >> 6;
    int lane = threadIdx.x & 63;
    if (w >= n) return;
    int c = lane & 15, g = lane >> 4;
    int beg = rowptr[w], end = rowptr[w + 1];
    float acc[8];
    #pragma unroll
    for (int j = 0; j < 8; ++j) acc[j] = 0.0f;
    for (int e0 = beg; e0 < end; e0 += 4) {
        int e = e0 + g;
        bool ok = e < end;
        uint2 en = ok ? ent[e] : make_uint2(0u, 0u);
        int ci = (int)en.x;
        float v = __uint_as_float(en.y);
        uint4 t = *(const uint4*)(tin + (size_t)ci * FD + c * 8);
        acc[0] += v * __uint_as_float(t.x << 16);
        acc[1] += v * __uint_as_float(t.x & 0xFFFF0000u);
        acc[2] += v * __uint_as_float(t.y << 16);
        acc[3] += v * __uint_as_float(t.y & 0xFFFF0000u);
        acc[4] += v * __uint_as_float(t.z << 16);
        acc[5] += v * __uint_as_float(t.z & 0xFFFF0000u);
        acc[6] += v * __uint_as_float(t.w << 16);
        acc[7] += v * __uint_as_float(t.w & 0xFFFF0000u);
    }
    #pragma unroll
    for (int j = 0; j < 8; ++j) {
        acc[j] += __shfl_xor(acc[j], 16, 64);
        acc[j] += __shfl_xor(acc[j], 32, 64);
    }
    if (g == 0) {
        uint4 r;
        float o[8];
        #pragma unroll
        for (int j = 0; j < 8; ++j) {
            float x = acc[j] + bias[c * 8 + j];
            o[j] = dorelu ? fmaxf(x, 0.0f) : x;
        }
        r.x = (unsigned)f2b(o[0]) | ((unsigned)f2b(o[1]) << 16);
        r.y = (unsigned)f2b(o[2]) | ((unsigned)f2b(o[3]) << 16);
        r.z = (unsigned)f2b(o[4]) | ((unsigned)f2b(o[5]) << 16);
        r.w = (unsigned)f2b(o[6]) | ((unsigned)f2b(o[7]) << 16);
        *(uint4*)(out + (size_t)w * FD + c * 8) = r;
    }
}

// one thread per (node, feature), 10 features, f32 (input 2 MB -> L2-resident)
__global__ void k_spmm10(const int* __restrict__ rowptr, const uint2* __restrict__ ent,
        const float* __restrict__ tin, const float* __restrict__ bias,
        float* __restrict__ out, int n) {
    int t = blockIdx.x * blockDim.x + threadIdx.x;
    int node = t / OUTD;
    int c = t - node * OUTD;
    if (node >= n) return;
    int beg = rowptr[node], end = rowptr[node + 1];
    float acc = 0.0f;
    for (int e = beg; e < end; ++e) {
        uint2 en = ent[e];
        acc += __uint_as_float(en.y) * tin[(size_t)en.x * OUTD + c];
    }
    out[(size_t)node * OUTD + c] = acc + bias[c];
}

// ---------------- pooling + log_softmax (1 block/graph) ----------------

__global__ __launch_bounds__(256) void k_poolfin(const float* __restrict__ h,
        const int* __restrict__ gstart, float* __restrict__ out) {
    int g = blockIdx.x;
    int beg = gstart[g], end = gstart[g + 1];
    int tid = threadIdx.x;
    int lane = tid & 63, wv = tid >> 6;
    float acc[OUTD];
    #pragma unroll
    for (int c = 0; c < OUTD; ++c) acc[c] = 0.0f;
    for (int i = beg + tid; i < end; i += 256) {
        const float* hp = h + (size_t)i * OUTD;
        #pragma unroll
        for (int c = 0; c < OUTD; ++c) acc[c] += hp[c];
    }
    #pragma unroll
    for (int off = 32; off >= 1; off >>= 1)
        #pragma unroll
        for (int c = 0; c < OUTD; ++c) acc[c] += __shfl_down(acc[c], off, 64);
    __shared__ float ws[4][OUTD];
    if (lane == 0)
        #pragma unroll
        for (int c = 0; c < OUTD; ++c) ws[wv][c] = acc[c];
    __syncthreads();
    if (tid == 0) {
        float cf = fmaxf((float)(end - beg), 1.0f);
        float v[OUTD], m = -1e30f;
        #pragma unroll
        for (int c = 0; c < OUTD; ++c) {
            v[c] = (ws[0][c] + ws[1][c] + ws[2][c] + ws[3][c]) / cf;
            m = fmaxf(m, v[c]);
        }
        float s = 0.0f;
        #pragma unroll
        for (int c = 0; c < OUTD; ++c) s += expf(v[c] - m);
        float l = logf(s);
        #pragma unroll
        for (int c = 0; c < OUTD; ++c) out[g * OUTD + c] = v[c] - m - l;
    }
}

// ---------------- launcher ----------------

extern "C" void kernel_launch(void* const* d_in, const int* in_sizes, int n_in,
                              void* d_out, int out_size, void* d_ws, size_t ws_size,
                              hipStream_t stream) {
    const float* x   = (const float*)d_in[0];
    const int*   ei  = (const int*)d_in[1];
    const float* ew  = (const float*)d_in[2];
    const int*   bat = (const int*)d_in[3];
    const float* W1  = (const float*)d_in[4];
    const float* b1  = (const float*)d_in[5];
    const float* W2  = (const float*)d_in[6];
    const float* b2  = (const float*)d_in[7];
    const float* W3  = (const float*)d_in[8];
    const float* b3  = (const float*)d_in[9];
    float* out = (float*)d_out;

    const int* src = ei;
    const int* dst = ei + EE;

    char* p = (char*)d_ws;
    auto alloc = [&](size_t bytes) -> void* {
        void* r = (void*)p;
        p += (bytes + 255) & ~(size_t)255;
        return r;
    };
    unsigned long long* packed = (unsigned long long*)alloc((size_t)NN * 8);
    int*            cnt    = (int*)  alloc((size_t)NN * 4);
    float*          dinv   = (float*)alloc((size_t)NN * 4);
    int*            rowptr = (int*)  alloc((size_t)(NN + 1) * 4);
    int*            fill   = (int*)  alloc((size_t)NN * 4);
    uint2*          ent    = (uint2*)alloc((size_t)(EE + NN) * 8);
    unsigned short* xbf    = (unsigned short*)alloc((size_t)NN * FD * 2);
    unsigned short* Wt1    = (unsigned short*)alloc((size_t)FD * FD * 2);
    unsigned short* Wt2    = (unsigned short*)alloc((size_t)FD * FD * 2);
    unsigned short* hA     = (unsigned short*)alloc((size_t)NN * FD * 2);
    unsigned short* hB     = (unsigned short*)alloc((size_t)NN * FD * 2);
    float*          bufC   = (float*)alloc((size_t)NN * OUTD * 4);
    float*          bufD   = (float*)alloc((size_t)NN * OUTD * 4);
    int*            bsum   = (int*)  alloc((size_t)(NB + 1) * 4);
    int*            gstart = (int*)  alloc((size_t)(GG + 1) * 4);
    (void)ws_size; (void)in_sizes; (void)n_in; (void)out_size;

    const int B = 256;
    // preprocessing
    k_init    <<<(NN + B - 1) / B, B, 0, stream>>>(packed, NN);
    k_degree  <<<(EE + B - 1) / B, B, 0, stream>>>(dst, ew, packed, EE);
    k_dinv    <<<(NN + B - 1) / B, B, 0, stream>>>(packed, cnt, dinv, NN);
    k_scanA   <<<NB, 1024, 0, stream>>>(cnt, rowptr, bsum, NN);
    k_scanB   <<<1, 64, 0, stream>>>(bsum, rowptr);
    k_scanC   <<<NB, 1024, 0, stream>>>(rowptr, fill, bsum, NN);
    k_fill    <<<(EE + B - 1) / B, B, 0, stream>>>(src, dst, ew, dinv, fill, ent, EE);
    k_selfloop<<<(NN + B - 1) / B, B, 0, stream>>>(rowptr, dinv, ent, NN);
    k_bounds  <<<(NN + B - 1) / B, B, 0, stream>>>(bat, gstart, NN);
    // dtype prep
    k_cvt     <<<(NN * FD / 8 + B - 1) / B, B, 0, stream>>>(x, xbf, NN * FD / 8);
    k_w128t   <<<(FD * FD + B - 1) / B, B, 0, stream>>>(W1, Wt1);
    k_w128t   <<<(FD * FD + B - 1) / B, B, 0, stream>>>(W2, Wt2);

    // layer 1
    k_gemm_bf<<<(NN + 63) / 64, B, 0, stream>>>(xbf, Wt1, hA, NN);
    k_spmm_bf<<<(NN * 64 + B - 1) / B, B, 0, stream>>>(rowptr, ent, hA, b1, hB, NN, 1);
    // layer 2
    k_gemm_bf<<<(NN + 63) / 64, B, 0, stream>>>(hB, Wt2, hA, NN);
    k_spmm_bf<<<(NN * 64 + B - 1) / B, B, 0, stream>>>(rowptr, ent, hA, b2, hB, NN, 1);
    // layer 3
    k_gemm10 <<<(NN + B - 1) / B, B, 0, stream>>>(hB, W3, bufC, NN);
    k_spmm10 <<<(NN * OUTD + B - 1) / B, B, 0, stream>>>(rowptr, ent, bufC, b3, bufD, NN);
    // pool + log_softmax
    k_poolfin<<<GG, 256, 0, stream>>>(bufD, gstart, out);
}

// Round 5
// 309.174 us; speedup vs baseline: 3.2361x; 1.1101x over previous
//
#include <hip/hip_runtime.h>
#include <math.h>

#define NN 50000
#define EE 800000
#define GG 64
#define FD 128
#define OUTD 10
#define NB 49           // ceil(NN/1024) scan blocks

typedef __attribute__((ext_vector_type(8))) short s8v;    // 8 bf16
typedef __attribute__((ext_vector_type(4))) float f4v;    // 4 f32 acc

static __device__ inline unsigned short f2b(float f) {    // f32 -> bf16 RNE
    unsigned int u = __float_as_uint(f);
    return (unsigned short)((u + 0x7FFFu + ((u >> 16) & 1u)) >> 16);
}

// packed degree accumulator: bits [0,44) = sum(w) in 2^-32 fixed point,
// bits [44,64) = edge count. One u64 atomic per edge; returned old value's
// count field doubles as the edge's rank within its CSR segment.
#define DEG_SCALE 4294967296.0
#define DEG_MASK  ((1ull << 44) - 1)

// ---------------- preprocessing ----------------

__global__ void k_init(unsigned long long* packed, int n) {
    int i = blockIdx.x * blockDim.x + threadIdx.x;
    if (i < n) packed[i] = (1ull << 44) | (1ull << 32);   // cnt=1, deg=1.0 (self-loop)
}

__global__ void k_degree(const int* __restrict__ dst, const float* __restrict__ w,
                         unsigned long long* packed, unsigned* __restrict__ rank, int e) {
    int i = blockIdx.x * blockDim.x + threadIdx.x;
    if (i >= e) return;
    unsigned long long q = (unsigned long long)((double)w[i] * DEG_SCALE + 0.5);
    unsigned long long old = atomicAdd(&packed[dst[i]], (1ull << 44) | q);
    rank[i] = (unsigned)(old >> 44) - 1u;   // 0-based rank among edges to this dst
}

// unpack: cnt for scan, dinv = 1/sqrt(deg)
__global__ void k_dinv(const unsigned long long* __restrict__ packed,
                       int* __restrict__ cnt, float* __restrict__ dinv, int n) {
    int i = blockIdx.x * blockDim.x + threadIdx.x;
    if (i >= n) return;
    unsigned long long p = packed[i];
    cnt[i] = (int)(p >> 44);
    float deg = (float)((double)(p & DEG_MASK) * (1.0 / DEG_SCALE));
    dinv[i] = 1.0f / sqrtf(deg);
}

// three-kernel scan: per-block scan -> scan of block sums -> add offsets
__global__ __launch_bounds__(1024) void k_scanA(const int* __restrict__ cnt,
        int* __restrict__ rowptr, int* __restrict__ blocksum, int n) {
    __shared__ int wtot[16];
    int tid = threadIdx.x;
    int i = blockIdx.x * 1024 + tid;
    int lane = tid & 63, wv = tid >> 6;
    int v = (i < n) ? cnt[i] : 0;
    int s = v;
    #pragma unroll
    for (int off = 1; off < 64; off <<= 1) {
        int u = __shfl_up(s, off, 64);
        if (lane >= off) s += u;
    }
    if (lane == 63) wtot[wv] = s;
    __syncthreads();
    int wpre = 0;
    for (int j = 0; j < wv; ++j) wpre += wtot[j];
    if (i < n) rowptr[i] = wpre + s - v;          // block-local exclusive
    if (tid == 1023) blocksum[blockIdx.x] = wpre + s;
}

__global__ void k_scanB(int* blocksum, int* rowptr) {  // 1 block, 64 threads
    int l = threadIdx.x;
    int v = (l < NB) ? blocksum[l] : 0;
    int s = v;
    #pragma unroll
    for (int off = 1; off < 64; off <<= 1) {
        int u = __shfl_up(s, off, 64);
        if (l >= off) s += u;
    }
    if (l < NB) blocksum[l] = s - v;              // exclusive, in place
    if (l == NB - 1) rowptr[NN] = s;              // total
}

__global__ __launch_bounds__(1024) void k_scanC(int* __restrict__ rowptr,
        const int* __restrict__ blocksum, int n) {
    int i = blockIdx.x * 1024 + threadIdx.x;
    if (i >= n) return;
    rowptr[i] += blocksum[blockIdx.x];
}

// atomic-free scatter: pos = rowptr[d] + rank. Self-loop goes at rowptr[d+1]-1.
__global__ void k_fill(const int* __restrict__ src, const int* __restrict__ dst,
                       const float* __restrict__ w, const float* __restrict__ dinv,
                       const int* __restrict__ rowptr, const unsigned* __restrict__ rank,
                       uint2* __restrict__ ent, int e) {
    int i = blockIdx.x * blockDim.x + threadIdx.x;
    if (i >= e) return;
    int s = src[i], d = dst[i];
    int pos = rowptr[d] + (int)rank[i];
    float v = dinv[s] * w[i] * dinv[d];
    ent[pos] = make_uint2((unsigned)s, __float_as_uint(v));
}

__global__ void k_selfloop(const int* __restrict__ rowptr, const float* __restrict__ dinv,
                           uint2* __restrict__ ent, int n) {
    int i = blockIdx.x * blockDim.x + threadIdx.x;
    if (i >= n) return;
    float di = dinv[i];
    ent[rowptr[i + 1] - 1] = make_uint2((unsigned)i, __float_as_uint(di * di));
}

// batch is sorted: gstart[g] = first node with batch >= g
__global__ void k_bounds(const int* __restrict__ batch, int* __restrict__ gstart, int n) {
    int i = blockIdx.x * blockDim.x + threadIdx.x;
    if (i >= n) return;
    int b = batch[i];
    int bp = (i == 0) ? -1 : batch[i - 1];
    for (int g = bp + 1; g <= b; ++g) gstart[g] = i;
    if (i == n - 1)
        for (int g = b + 1; g <= GG; ++g) gstart[g] = n;
}

// ---------------- dtype conversion ----------------

__global__ void k_cvt(const float* __restrict__ in, unsigned short* __restrict__ out, int n8) {
    int i = blockIdx.x * blockDim.x + threadIdx.x;
    if (i >= n8) return;
    const float4* p = (const float4*)in + (size_t)i * 2;
    float4 a = p[0], b = p[1];
    uint4 r;
    r.x = (unsigned)f2b(a.x) | ((unsigned)f2b(a.y) << 16);
    r.y = (unsigned)f2b(a.z) | ((unsigned)f2b(a.w) << 16);
    r.z = (unsigned)f2b(b.x) | ((unsigned)f2b(b.y) << 16);
    r.w = (unsigned)f2b(b.z) | ((unsigned)f2b(b.w) << 16);
    *((uint4*)out + i) = r;
}

// W f32 [128k x 128n] -> Wt bf16 [128n x 128k]
__global__ void k_w128t(const float* __restrict__ W, unsigned short* __restrict__ Wt) {
    int i = blockIdx.x * blockDim.x + threadIdx.x;   // i = n*128 + k
    if (i >= FD * FD) return;
    int nn = i >> 7, k = i & 127;
    Wt[i] = f2b(W[k * FD + nn]);
}

// ---------------- dense transform: bf16 MFMA GEMM ----------------
// out[n][128] = A[n][128] @ W[128][128]; 4 waves/block, 16 rows/wave.
__global__ __launch_bounds__(256) void k_gemm_bf(const unsigned short* __restrict__ A,
        const unsigned short* __restrict__ Wt, unsigned short* __restrict__ out, int n) {
    int tid = threadIdx.x;
    int wave = tid >> 6, lane = tid & 63;
    int quad = lane >> 4, c16 = lane & 15;
    int rowbase = blockIdx.x * 64 + wave * 16;
    int rowA = rowbase + c16;
    if (rowA >= n) rowA = n - 1;                  // clamp loads; stores guarded
    f4v acc[8];
    #pragma unroll
    for (int t = 0; t < 8; ++t) acc[t] = (f4v){0.f, 0.f, 0.f, 0.f};

    #pragma unroll
    for (int k0 = 0; k0 < 128; k0 += 32) {
        s8v a = *(const s8v*)(A + (size_t)rowA * FD + k0 + quad * 8);
        #pragma unroll
        for (int t = 0; t < 8; ++t) {
            s8v b = *(const s8v*)(Wt + (size_t)(t * 16 + c16) * FD + k0 + quad * 8);
            acc[t] = __builtin_amdgcn_mfma_f32_16x16x32_bf16(a, b, acc[t], 0, 0, 0);
        }
    }
    #pragma unroll
    for (int t = 0; t < 8; ++t) {
        #pragma unroll
        for (int r = 0; r < 4; ++r) {
            int row = rowbase + quad * 4 + r;
            if (row < n) out[(size_t)row * FD + t * 16 + c16] = f2b(acc[t][r]);
        }
    }
}

// out[n][10] = A[n][128] @ W[128][10], A bf16, W f32 (LDS), out f32
__global__ void k_gemm10(const unsigned short* __restrict__ A, const float* __restrict__ W,
                         float* __restrict__ out, int n) {
    __shared__ float Ws[FD * OUTD];
    int tid = threadIdx.x;
    for (int i = tid; i < FD * OUTD; i += blockDim.x) Ws[i] = W[i];
    __syncthreads();
    int i = blockIdx.x * blockDim.x + tid;
    if (i >= n) return;
    float acc[OUTD];
    #pragma unroll
    for (int c = 0; c < OUTD; ++c) acc[c] = 0.0f;
    const unsigned short* a = A + (size_t)i * FD;
    for (int k0 = 0; k0 < FD; k0 += 8) {
        uint4 t = *(const uint4*)(a + k0);
        float av[8];
        av[0] = __uint_as_float(t.x << 16); av[1] = __uint_as_float(t.x & 0xFFFF0000u);
        av[2] = __uint_as_float(t.y << 16); av[3] = __uint_as_float(t.y & 0xFFFF0000u);
        av[4] = __uint_as_float(t.z << 16); av[5] = __uint_as_float(t.z & 0xFFFF0000u);
        av[6] = __uint_as_float(t.w << 16); av[7] = __uint_as_float(t.w & 0xFFFF0000u);
        #pragma unroll
        for (int j = 0; j < 8; ++j)
            #pragma unroll
            for (int c = 0; c < OUTD; ++c) acc[c] += av[j] * Ws[(k0 + j) * OUTD + c];
    }
    float* o = out + (size_t)i * OUTD;
    #pragma unroll
    for (int c = 0; c < OUTD; ++c) o[c] = acc[c];
}

// ---------------- sparse aggregation, bf16 features ----------------
// one wave per node; 8 edges in flight per iter (2x unroll of 16 lanes x 16B)
__global__ __launch_bounds__(256) void k_spmm_bf(const int* __restrict__ rowptr,
        const uint2* __restrict__ ent, const unsigned short* __restrict__ tin,
        const float* __restrict__ bias, unsigned short* __restrict__ out,
        int n, int dorelu) {
    int w = (blockIdx.x * blockDim.x + threadIdx.x) >> 6;
    int lane = threadIdx.x & 63;
    if (w >= n) return;
    int c = lane & 15, g = lane >> 4;
    int beg = rowptr[w], end = rowptr[w + 1];
    float acc[8];
    #pragma unroll
    for (int j = 0; j < 8; ++j) acc[j] = 0.0f;
    for (int e0 = beg; e0 < end; e0 += 8) {
        int e1 = e0 + g, e2 = e0 + 4 + g;
        uint2 en1 = (e1 < end) ? ent[e1] : make_uint2(0u, 0u);
        uint2 en2 = (e2 < end) ? ent[e2] : make_uint2(0u, 0u);
        uint4 t1 = *(const uint4*)(tin + (size_t)en1.x * FD + c * 8);
        uint4 t2 = *(const uint4*)(tin + (size_t)en2.x * FD + c * 8);
        float v1 = __uint_as_float(en1.y), v2 = __uint_as_float(en2.y);
        acc[0] += v1 * __uint_as_float(t1.x << 16);
        acc[1] += v1 * __uint_as_float(t1.x & 0xFFFF0000u);
        acc[2] += v1 * __uint_as_float(t1.y << 16);
        acc[3] += v1 * __uint_as_float(t1.y & 0xFFFF0000u);
        acc[4] += v1 * __uint_as_float(t1.z << 16);
        acc[5] += v1 * __uint_as_float(t1.z & 0xFFFF0000u);
        acc[6] += v1 * __uint_as_float(t1.w << 16);
        acc[7] += v1 * __uint_as_float(t1.w & 0xFFFF0000u);
        acc[0] += v2 * __uint_as_float(t2.x << 16);
        acc[1] += v2 * __uint_as_float(t2.x & 0xFFFF0000u);
        acc[2] += v2 * __uint_as_float(t2.y << 16);
        acc[3] += v2 * __uint_as_float(t2.y & 0xFFFF0000u);
        acc[4] += v2 * __uint_as_float(t2.z << 16);
        acc[5] += v2 * __uint_as_float(t2.z & 0xFFFF0000u);
        acc[6] += v2 * __uint_as_float(t2.w << 16);
        acc[7] += v2 * __uint_as_float(t2.w & 0xFFFF0000u);
    }
    #pragma unroll
    for (int j = 0; j < 8; ++j) {
        acc[j] += __shfl_xor(acc[j], 16, 64);
        acc[j] += __shfl_xor(acc[j], 32, 64);
    }
    if (g == 0) {
        uint4 r;
        float o[8];
        #pragma unroll
        for (int j = 0; j < 8; ++j) {
            float x = acc[j] + bias[c * 8 + j];
            o[j] = dorelu ? fmaxf(x, 0.0f) : x;
        }
        r.x = (unsigned)f2b(o[0]) | ((unsigned)f2b(o[1]) << 16);
        r.y = (unsigned)f2b(o[2]) | ((unsigned)f2b(o[3]) << 16);
        r.z = (unsigned)f2b(o[4]) | ((unsigned)f2b(o[5]) << 16);
        r.w = (unsigned)f2b(o[6]) | ((unsigned)f2b(o[7]) << 16);
        *(uint4*)(out + (size_t)w * FD + c * 8) = r;
    }
}

// one thread per (node, feature), 10 features, f32 (input 2 MB -> L2-resident)
__global__ void k_spmm10(const int* __restrict__ rowptr, const uint2* __restrict__ ent,
        const float* __restrict__ tin, const float* __restrict__ bias,
        float* __restrict__ out, int n) {
    int t = blockIdx.x * blockDim.x + threadIdx.x;
    int node = t / OUTD;
    int c = t - node * OUTD;
    if (node >= n) return;
    int beg = rowptr[node], end = rowptr[node + 1];
    float acc = 0.0f;
    for (int e = beg; e < end; ++e) {
        uint2 en = ent[e];
        acc += __uint_as_float(en.y) * tin[(size_t)en.x * OUTD + c];
    }
    out[(size_t)node * OUTD + c] = acc + bias[c];
}

// ---------------- pooling + log_softmax (1 block/graph) ----------------

__global__ __launch_bounds__(256) void k_poolfin(const float* __restrict__ h,
        const int* __restrict__ gstart, float* __restrict__ out) {
    int g = blockIdx.x;
    int beg = gstart[g], end = gstart[g + 1];
    int tid = threadIdx.x;
    int lane = tid & 63, wv = tid >> 6;
    float acc[OUTD];
    #pragma unroll
    for (int c = 0; c < OUTD; ++c) acc[c] = 0.0f;
    for (int i = beg + tid; i < end; i += 256) {
        const float* hp = h + (size_t)i * OUTD;
        #pragma unroll
        for (int c = 0; c < OUTD; ++c) acc[c] += hp[c];
    }
    #pragma unroll
    for (int off = 32; off >= 1; off >>= 1)
        #pragma unroll
        for (int c = 0; c < OUTD; ++c) acc[c] += __shfl_down(acc[c], off, 64);
    __shared__ float ws[4][OUTD];
    if (lane == 0)
        #pragma unroll
        for (int c = 0; c < OUTD; ++c) ws[wv][c] = acc[c];
    __syncthreads();
    if (tid == 0) {
        float cf = fmaxf((float)(end - beg), 1.0f);
        float v[OUTD], m = -1e30f;
        #pragma unroll
        for (int c = 0; c < OUTD; ++c) {
            v[c] = (ws[0][c] + ws[1][c] + ws[2][c] + ws[3][c]) / cf;
            m = fmaxf(m, v[c]);
        }
        float s = 0.0f;
        #pragma unroll
        for (int c = 0; c < OUTD; ++c) s += expf(v[c] - m);
        float l = logf(s);
        #pragma unroll
        for (int c = 0; c < OUTD; ++c) out[g * OUTD + c] = v[c] - m - l;
    }
}

// ---------------- launcher ----------------

extern "C" void kernel_launch(void* const* d_in, const int* in_sizes, int n_in,
                              void* d_out, int out_size, void* d_ws, size_t ws_size,
                              hipStream_t stream) {
    const float* x   = (const float*)d_in[0];
    const int*   ei  = (const int*)d_in[1];
    const float* ew  = (const float*)d_in[2];
    const int*   bat = (const int*)d_in[3];
    const float* W1  = (const float*)d_in[4];
    const float* b1  = (const float*)d_in[5];
    const float* W2  = (const float*)d_in[6];
    const float* b2  = (const float*)d_in[7];
    const float* W3  = (const float*)d_in[8];
    const float* b3  = (const float*)d_in[9];
    float* out = (float*)d_out;

    const int* src = ei;
    const int* dst = ei + EE;

    char* p = (char*)d_ws;
    auto alloc = [&](size_t bytes) -> void* {
        void* r = (void*)p;
        p += (bytes + 255) & ~(size_t)255;
        return r;
    };
    unsigned long long* packed = (unsigned long long*)alloc((size_t)NN * 8);
    int*            cnt    = (int*)  alloc((size_t)NN * 4);
    float*          dinv   = (float*)alloc((size_t)NN * 4);
    int*            rowptr = (int*)  alloc((size_t)(NN + 1) * 4);
    unsigned*       rank   = (unsigned*)alloc((size_t)EE * 4);
    uint2*          ent    = (uint2*)alloc((size_t)(EE + NN) * 8);
    unsigned short* xbf    = (unsigned short*)alloc((size_t)NN * FD * 2);
    unsigned short* Wt1    = (unsigned short*)alloc((size_t)FD * FD * 2);
    unsigned short* Wt2    = (unsigned short*)alloc((size_t)FD * FD * 2);
    unsigned short* hA     = (unsigned short*)alloc((size_t)NN * FD * 2);
    unsigned short* hB     = (unsigned short*)alloc((size_t)NN * FD * 2);
    float*          bufC   = (float*)alloc((size_t)NN * OUTD * 4);
    float*          bufD   = (float*)alloc((size_t)NN * OUTD * 4);
    int*            bsum   = (int*)  alloc((size_t)(NB + 1) * 4);
    int*            gstart = (int*)  alloc((size_t)(GG + 1) * 4);
    (void)ws_size; (void)in_sizes; (void)n_in; (void)out_size;

    const int B = 256;
    // preprocessing
    k_init    <<<(NN + B - 1) / B, B, 0, stream>>>(packed, NN);
    k_degree  <<<(EE + B - 1) / B, B, 0, stream>>>(dst, ew, packed, rank, EE);
    k_dinv    <<<(NN + B - 1) / B, B, 0, stream>>>(packed, cnt, dinv, NN);
    k_scanA   <<<NB, 1024, 0, stream>>>(cnt, rowptr, bsum, NN);
    k_scanB   <<<1, 64, 0, stream>>>(bsum, rowptr);
    k_scanC   <<<NB, 1024, 0, stream>>>(rowptr, bsum, NN);
    k_fill    <<<(EE + B - 1) / B, B, 0, stream>>>(src, dst, ew, dinv, rowptr, rank, ent, EE);
    k_selfloop<<<(NN + B - 1) / B, B, 0, stream>>>(rowptr, dinv, ent, NN);
    k_bounds  <<<(NN + B - 1) / B, B, 0, stream>>>(bat, gstart, NN);
    // dtype prep
    k_cvt     <<<(NN * FD / 8 + B - 1) / B, B, 0, stream>>>(x, xbf, NN * FD / 8);
    k_w128t   <<<(FD * FD + B - 1) / B, B, 0, stream>>>(W1, Wt1);
    k_w128t   <<<(FD * FD + B - 1) / B, B, 0, stream>>>(W2, Wt2);

    // layer 1
    k_gemm_bf<<<(NN + 63) / 64, B, 0, stream>>>(xbf, Wt1, hA, NN);
    k_spmm_bf<<<(NN * 64 + B - 1) / B, B, 0, stream>>>(rowptr, ent, hA, b1, hB, NN, 1);
    // layer 2
    k_gemm_bf<<<(NN + 63) / 64, B, 0, stream>>>(hB, Wt2, hA, NN);
    k_spmm_bf<<<(NN * 64 + B - 1) / B, B, 0, stream>>>(rowptr, ent, hA, b2, hB, NN, 1);
    // layer 3
    k_gemm10 <<<(NN + B - 1) / B, B, 0, stream>>>(hB, W3, bufC, NN);
    k_spmm10 <<<(NN * OUTD + B - 1) / B, B, 0, stream>>>(rowptr, ent, bufC, b3, bufD, NN);
    // pool + log_softmax
    k_poolfin<<<GG, 256, 0, stream>>>(bufD, gstart, out);
}

// Round 6
// 297.311 us; speedup vs baseline: 3.3652x; 1.0399x over previous
//
#include <hip/hip_runtime.h>
#include <math.h>

#define NN 50000
#define EE 800000
#define GG 64
#define FD 128
#define OUTD 10
#define NB 49           // ceil(NN/1024) scan blocks

typedef __attribute__((ext_vector_type(8))) short s8v;    // 8 bf16
typedef __attribute__((ext_vector_type(4))) float f4v;    // 4 f32 acc

static __device__ inline unsigned short f2b(float f) {    // f32 -> bf16 RNE
    unsigned int u = __float_as_uint(f);
    return (unsigned short)((u + 0x7FFFu + ((u >> 16) & 1u)) >> 16);
}

// packed degree accumulator: bits [0,44) = sum(w) in 2^-32 fixed point,
// bits [44,64) = edge count. One u64 atomic per edge; returned old value's
// count field doubles as the edge's rank within its CSR segment.
#define DEG_SCALE 4294967296.0
#define DEG_MASK  ((1ull << 44) - 1)

// ---------------- preprocessing ----------------

// fused: init packed accumulators + transpose/convert W1,W2 to bf16
__global__ void k_prep(unsigned long long* packed, const float* __restrict__ W1,
                       const float* __restrict__ W2, unsigned short* __restrict__ Wt1,
                       unsigned short* __restrict__ Wt2, int n) {
    int i = blockIdx.x * blockDim.x + threadIdx.x;
    if (i < n) packed[i] = (1ull << 44) | (1ull << 32);   // cnt=1, deg=1.0 (self-loop)
    if (i < FD * FD) {
        int nn = i >> 7, k = i & 127;
        Wt1[i] = f2b(W1[k * FD + nn]);
        Wt2[i] = f2b(W2[k * FD + nn]);
    }
}

__global__ void k_degree(const int* __restrict__ dst, const float* __restrict__ w,
                         unsigned long long* packed, unsigned* __restrict__ rank, int e) {
    int i = blockIdx.x * blockDim.x + threadIdx.x;
    if (i >= e) return;
    unsigned long long q = (unsigned long long)((double)w[i] * DEG_SCALE + 0.5);
    unsigned long long old = atomicAdd(&packed[dst[i]], (1ull << 44) | q);
    rank[i] = (unsigned)(old >> 44) - 1u;   // 0-based rank among edges to this dst
}

// fused scanA: reads packed (cnt field), also computes dinv = 1/sqrt(deg)
__global__ __launch_bounds__(1024) void k_scanA(const unsigned long long* __restrict__ packed,
        int* __restrict__ rowptr, int* __restrict__ blocksum,
        float* __restrict__ dinv, int n) {
    __shared__ int wtot[16];
    int tid = threadIdx.x;
    int i = blockIdx.x * 1024 + tid;
    int lane = tid & 63, wv = tid >> 6;
    int v = 0;
    if (i < n) {
        unsigned long long p = packed[i];
        v = (int)(p >> 44);
        float deg = (float)((double)(p & DEG_MASK) * (1.0 / DEG_SCALE));
        dinv[i] = 1.0f / sqrtf(deg);
    }
    int s = v;
    #pragma unroll
    for (int off = 1; off < 64; off <<= 1) {
        int u = __shfl_up(s, off, 64);
        if (lane >= off) s += u;
    }
    if (lane == 63) wtot[wv] = s;
    __syncthreads();
    int wpre = 0;
    for (int j = 0; j < wv; ++j) wpre += wtot[j];
    if (i < n) rowptr[i] = wpre + s - v;          // block-local exclusive
    if (tid == 1023) blocksum[blockIdx.x] = wpre + s;
}

__global__ void k_scanB(int* blocksum, int* rowptr) {  // 1 block, 64 threads
    int l = threadIdx.x;
    int v = (l < NB) ? blocksum[l] : 0;
    int s = v;
    #pragma unroll
    for (int off = 1; off < 64; off <<= 1) {
        int u = __shfl_up(s, off, 64);
        if (l >= off) s += u;
    }
    if (l < NB) blocksum[l] = s - v;              // exclusive, in place
    if (l == NB - 1) rowptr[NN] = s;              // total
}

// fused scanC: finalize rowptr + write the self-loop entry at rowptr[i+1]-1
__global__ __launch_bounds__(1024) void k_scanC(int* __restrict__ rowptr,
        const int* __restrict__ blocksum, const unsigned long long* __restrict__ packed,
        const float* __restrict__ dinv, uint2* __restrict__ ent, int n) {
    int i = blockIdx.x * 1024 + threadIdx.x;
    if (i >= n) return;
    int r = rowptr[i] + blocksum[blockIdx.x];
    rowptr[i] = r;
    int cnt = (int)(packed[i] >> 44);
    float di = dinv[i];
    ent[r + cnt - 1] = make_uint2((unsigned)i, __float_as_uint(di * di));
}

// atomic-free scatter: pos = rowptr[d] + rank
__global__ void k_fill(const int* __restrict__ src, const int* __restrict__ dst,
                       const float* __restrict__ w, const float* __restrict__ dinv,
                       const int* __restrict__ rowptr, const unsigned* __restrict__ rank,
                       uint2* __restrict__ ent, int e) {
    int i = blockIdx.x * blockDim.x + threadIdx.x;
    if (i >= e) return;
    int s = src[i], d = dst[i];
    int pos = rowptr[d] + (int)rank[i];
    float v = dinv[s] * w[i] * dinv[d];
    ent[pos] = make_uint2((unsigned)s, __float_as_uint(v));
}

// batch is sorted: gstart[g] = first node with batch >= g
__global__ void k_bounds(const int* __restrict__ batch, int* __restrict__ gstart, int n) {
    int i = blockIdx.x * blockDim.x + threadIdx.x;
    if (i >= n) return;
    int b = batch[i];
    int bp = (i == 0) ? -1 : batch[i - 1];
    for (int g = bp + 1; g <= b; ++g) gstart[g] = i;
    if (i == n - 1)
        for (int g = b + 1; g <= GG; ++g) gstart[g] = n;
}

// ---------------- dense transforms: bf16 MFMA GEMM ----------------
// out[n][128] = A[n][128] @ W[128][128]; 4 waves/block, 16 rows/wave.
// Layer-1 variant reads f32 A and converts in-register (kills the cvt kernel).
__global__ __launch_bounds__(256) void k_gemm_f32in(const float* __restrict__ A,
        const unsigned short* __restrict__ Wt, unsigned short* __restrict__ out, int n) {
    int tid = threadIdx.x;
    int wave = tid >> 6, lane = tid & 63;
    int quad = lane >> 4, c16 = lane & 15;
    int rowbase = blockIdx.x * 64 + wave * 16;
    int rowA = rowbase + c16;
    if (rowA >= n) rowA = n - 1;
    f4v acc[8];
    #pragma unroll
    for (int t = 0; t < 8; ++t) acc[t] = (f4v){0.f, 0.f, 0.f, 0.f};

    #pragma unroll
    for (int k0 = 0; k0 < 128; k0 += 32) {
        const float* ap = A + (size_t)rowA * FD + k0 + quad * 8;
        float4 a0 = *(const float4*)ap;
        float4 a1 = *(const float4*)(ap + 4);
        s8v a;
        a[0] = (short)f2b(a0.x); a[1] = (short)f2b(a0.y);
        a[2] = (short)f2b(a0.z); a[3] = (short)f2b(a0.w);
        a[4] = (short)f2b(a1.x); a[5] = (short)f2b(a1.y);
        a[6] = (short)f2b(a1.z); a[7] = (short)f2b(a1.w);
        #pragma unroll
        for (int t = 0; t < 8; ++t) {
            s8v b = *(const s8v*)(Wt + (size_t)(t * 16 + c16) * FD + k0 + quad * 8);
            acc[t] = __builtin_amdgcn_mfma_f32_16x16x32_bf16(a, b, acc[t], 0, 0, 0);
        }
    }
    #pragma unroll
    for (int t = 0; t < 8; ++t) {
        #pragma unroll
        for (int r = 0; r < 4; ++r) {
            int row = rowbase + quad * 4 + r;
            if (row < n) out[(size_t)row * FD + t * 16 + c16] = f2b(acc[t][r]);
        }
    }
}

__global__ __launch_bounds__(256) void k_gemm_bf(const unsigned short* __restrict__ A,
        const unsigned short* __restrict__ Wt, unsigned short* __restrict__ out, int n) {
    int tid = threadIdx.x;
    int wave = tid >> 6, lane = tid & 63;
    int quad = lane >> 4, c16 = lane & 15;
    int rowbase = blockIdx.x * 64 + wave * 16;
    int rowA = rowbase + c16;
    if (rowA >= n) rowA = n - 1;
    f4v acc[8];
    #pragma unroll
    for (int t = 0; t < 8; ++t) acc[t] = (f4v){0.f, 0.f, 0.f, 0.f};

    #pragma unroll
    for (int k0 = 0; k0 < 128; k0 += 32) {
        s8v a = *(const s8v*)(A + (size_t)rowA * FD + k0 + quad * 8);
        #pragma unroll
        for (int t = 0; t < 8; ++t) {
            s8v b = *(const s8v*)(Wt + (size_t)(t * 16 + c16) * FD + k0 + quad * 8);
            acc[t] = __builtin_amdgcn_mfma_f32_16x16x32_bf16(a, b, acc[t], 0, 0, 0);
        }
    }
    #pragma unroll
    for (int t = 0; t < 8; ++t) {
        #pragma unroll
        for (int r = 0; r < 4; ++r) {
            int row = rowbase + quad * 4 + r;
            if (row < n) out[(size_t)row * FD + t * 16 + c16] = f2b(acc[t][r]);
        }
    }
}

// out[n][10] = A[n][128] @ W[128][10], A bf16, W f32 (LDS), out f32
__global__ void k_gemm10(const unsigned short* __restrict__ A, const float* __restrict__ W,
                         float* __restrict__ out, int n) {
    __shared__ float Ws[FD * OUTD];
    int tid = threadIdx.x;
    for (int i = tid; i < FD * OUTD; i += blockDim.x) Ws[i] = W[i];
    __syncthreads();
    int i = blockIdx.x * blockDim.x + tid;
    if (i >= n) return;
    float acc[OUTD];
    #pragma unroll
    for (int c = 0; c < OUTD; ++c) acc[c] = 0.0f;
    const unsigned short* a = A + (size_t)i * FD;
    for (int k0 = 0; k0 < FD; k0 += 8) {
        uint4 t = *(const uint4*)(a + k0);
        float av[8];
        av[0] = __uint_as_float(t.x << 16); av[1] = __uint_as_float(t.x & 0xFFFF0000u);
        av[2] = __uint_as_float(t.y << 16); av[3] = __uint_as_float(t.y & 0xFFFF0000u);
        av[4] = __uint_as_float(t.z << 16); av[5] = __uint_as_float(t.z & 0xFFFF0000u);
        av[6] = __uint_as_float(t.w << 16); av[7] = __uint_as_float(t.w & 0xFFFF0000u);
        #pragma unroll
        for (int j = 0; j < 8; ++j)
            #pragma unroll
            for (int c = 0; c < OUTD; ++c) acc[c] += av[j] * Ws[(k0 + j) * OUTD + c];
    }
    float* o = out + (size_t)i * OUTD;
    #pragma unroll
    for (int c = 0; c < OUTD; ++c) o[c] = acc[c];
}

// ---------------- sparse aggregation, bf16 features ----------------
// one wave per node; 16 edges in flight per iter (4x unroll of 4 groups x 16B)
__global__ __launch_bounds__(256) void k_spmm_bf(const int* __restrict__ rowptr,
        const uint2* __restrict__ ent, const unsigned short* __restrict__ tin,
        const float* __restrict__ bias, unsigned short* __restrict__ out,
        int n, int dorelu) {
    int w = (blockIdx.x * blockDim.x + threadIdx.x) >> 6;
    int lane = threadIdx.x & 63;
    if (w >= n) return;
    int c = lane & 15, g = lane >> 4;
    int beg = rowptr[w], end = rowptr[w + 1];
    float acc[8];
    #pragma unroll
    for (int j = 0; j < 8; ++j) acc[j] = 0.0f;
    for (int e0 = beg; e0 < end; e0 += 16) {
        uint2 en[4];
        uint4 t[4];
        #pragma unroll
        for (int u = 0; u < 4; ++u) {
            int e = e0 + 4 * u + g;
            en[u] = (e < end) ? ent[e] : make_uint2(0u, 0u);
        }
        #pragma unroll
        for (int u = 0; u < 4; ++u)
            t[u] = *(const uint4*)(tin + (size_t)en[u].x * FD + c * 8);
        #pragma unroll
        for (int u = 0; u < 4; ++u) {
            float v = __uint_as_float(en[u].y);
            acc[0] += v * __uint_as_float(t[u].x << 16);
            acc[1] += v * __uint_as_float(t[u].x & 0xFFFF0000u);
            acc[2] += v * __uint_as_float(t[u].y << 16);
            acc[3] += v * __uint_as_float(t[u].y & 0xFFFF0000u);
            acc[4] += v * __uint_as_float(t[u].z << 16);
            acc[5] += v * __uint_as_float(t[u].z & 0xFFFF0000u);
            acc[6] += v * __uint_as_float(t[u].w << 16);
            acc[7] += v * __uint_as_float(t[u].w & 0xFFFF0000u);
        }
    }
    #pragma unroll
    for (int j = 0; j < 8; ++j) {
        acc[j] += __shfl_xor(acc[j], 16, 64);
        acc[j] += __shfl_xor(acc[j], 32, 64);
    }
    if (g == 0) {
        uint4 r;
        float o[8];
        #pragma unroll
        for (int j = 0; j < 8; ++j) {
            float x = acc[j] + bias[c * 8 + j];
            o[j] = dorelu ? fmaxf(x, 0.0f) : x;
        }
        r.x = (unsigned)f2b(o[0]) | ((unsigned)f2b(o[1]) << 16);
        r.y = (unsigned)f2b(o[2]) | ((unsigned)f2b(o[3]) << 16);
        r.z = (unsigned)f2b(o[4]) | ((unsigned)f2b(o[5]) << 16);
        r.w = (unsigned)f2b(o[6]) | ((unsigned)f2b(o[7]) << 16);
        *(uint4*)(out + (size_t)w * FD + c * 8) = r;
    }
}

// one thread per (node, feature), 10 features, f32 (input 2 MB -> L2-resident)
__global__ void k_spmm10(const int* __restrict__ rowptr, const uint2* __restrict__ ent,
        const float* __restrict__ tin, const float* __restrict__ bias,
        float* __restrict__ out, int n) {
    int t = blockIdx.x * blockDim.x + threadIdx.x;
    int node = t / OUTD;
    int c = t - node * OUTD;
    if (node >= n) return;
    int beg = rowptr[node], end = rowptr[node + 1];
    float acc = 0.0f;
    for (int e = beg; e < end; ++e) {
        uint2 en = ent[e];
        acc += __uint_as_float(en.y) * tin[(size_t)en.x * OUTD + c];
    }
    out[(size_t)node * OUTD + c] = acc + bias[c];
}

// ---------------- pooling + log_softmax (1 block/graph) ----------------

__global__ __launch_bounds__(256) void k_poolfin(const float* __restrict__ h,
        const int* __restrict__ gstart, float* __restrict__ out) {
    int g = blockIdx.x;
    int beg = gstart[g], end = gstart[g + 1];
    int tid = threadIdx.x;
    int lane = tid & 63, wv = tid >> 6;
    float acc[OUTD];
    #pragma unroll
    for (int c = 0; c < OUTD; ++c) acc[c] = 0.0f;
    for (int i = beg + tid; i < end; i += 256) {
        const float* hp = h + (size_t)i * OUTD;
        #pragma unroll
        for (int c = 0; c < OUTD; ++c) acc[c] += hp[c];
    }
    #pragma unroll
    for (int off = 32; off >= 1; off >>= 1)
        #pragma unroll
        for (int c = 0; c < OUTD; ++c) acc[c] += __shfl_down(acc[c], off, 64);
    __shared__ float ws[4][OUTD];
    if (lane == 0)
        #pragma unroll
        for (int c = 0; c < OUTD; ++c) ws[wv][c] = acc[c];
    __syncthreads();
    if (tid == 0) {
        float cf = fmaxf((float)(end - beg), 1.0f);
        float v[OUTD], m = -1e30f;
        #pragma unroll
        for (int c = 0; c < OUTD; ++c) {
            v[c] = (ws[0][c] + ws[1][c] + ws[2][c] + ws[3][c]) / cf;
            m = fmaxf(m, v[c]);
        }
        float s = 0.0f;
        #pragma unroll
        for (int c = 0; c < OUTD; ++c) s += expf(v[c] - m);
        float l = logf(s);
        #pragma unroll
        for (int c = 0; c < OUTD; ++c) out[g * OUTD + c] = v[c] - m - l;
    }
}

// ---------------- launcher ----------------

extern "C" void kernel_launch(void* const* d_in, const int* in_sizes, int n_in,
                              void* d_out, int out_size, void* d_ws, size_t ws_size,
                              hipStream_t stream) {
    const float* x   = (const float*)d_in[0];
    const int*   ei  = (const int*)d_in[1];
    const float* ew  = (const float*)d_in[2];
    const int*   bat = (const int*)d_in[3];
    const float* W1  = (const float*)d_in[4];
    const float* b1  = (const float*)d_in[5];
    const float* W2  = (const float*)d_in[6];
    const float* b2  = (const float*)d_in[7];
    const float* W3  = (const float*)d_in[8];
    const float* b3  = (const float*)d_in[9];
    float* out = (float*)d_out;

    const int* src = ei;
    const int* dst = ei + EE;

    char* p = (char*)d_ws;
    auto alloc = [&](size_t bytes) -> void* {
        void* r = (void*)p;
        p += (bytes + 255) & ~(size_t)255;
        return r;
    };
    unsigned long long* packed = (unsigned long long*)alloc((size_t)NN * 8);
    float*          dinv   = (float*)alloc((size_t)NN * 4);
    int*            rowptr = (int*)  alloc((size_t)(NN + 1) * 4);
    unsigned*       rank   = (unsigned*)alloc((size_t)EE * 4);
    uint2*          ent    = (uint2*)alloc((size_t)(EE + NN) * 8);
    unsigned short* Wt1    = (unsigned short*)alloc((size_t)FD * FD * 2);
    unsigned short* Wt2    = (unsigned short*)alloc((size_t)FD * FD * 2);
    unsigned short* hA     = (unsigned short*)alloc((size_t)NN * FD * 2);
    unsigned short* hB     = (unsigned short*)alloc((size_t)NN * FD * 2);
    float*          bufC   = (float*)alloc((size_t)NN * OUTD * 4);
    float*          bufD   = (float*)alloc((size_t)NN * OUTD * 4);
    int*            bsum   = (int*)  alloc((size_t)(NB + 1) * 4);
    int*            gstart = (int*)  alloc((size_t)(GG + 1) * 4);
    (void)ws_size; (void)in_sizes; (void)n_in; (void)out_size;

    const int B = 256;
    // preprocessing
    k_prep  <<<(NN + B - 1) / B, B, 0, stream>>>(packed, W1, W2, Wt1, Wt2, NN);
    k_degree<<<(EE + B - 1) / B, B, 0, stream>>>(dst, ew, packed, rank, EE);
    k_scanA <<<NB, 1024, 0, stream>>>(packed, rowptr, bsum, dinv, NN);
    k_scanB <<<1, 64, 0, stream>>>(bsum, rowptr);
    k_scanC <<<NB, 1024, 0, stream>>>(rowptr, bsum, packed, dinv, ent, NN);
    k_fill  <<<(EE + B - 1) / B, B, 0, stream>>>(src, dst, ew, dinv, rowptr, rank, ent, EE);
    k_bounds<<<(NN + B - 1) / B, B, 0, stream>>>(bat, gstart, NN);

    // layer 1 (reads f32 x directly)
    k_gemm_f32in<<<(NN + 63) / 64, B, 0, stream>>>(x, Wt1, hA, NN);
    k_spmm_bf   <<<(NN * 64 + B - 1) / B, B, 0, stream>>>(rowptr, ent, hA, b1, hB, NN, 1);
    // layer 2
    k_gemm_bf   <<<(NN + 63) / 64, B, 0, stream>>>(hB, Wt2, hA, NN);
    k_spmm_bf   <<<(NN * 64 + B - 1) / B, B, 0, stream>>>(rowptr, ent, hA, b2, hB, NN, 1);
    // layer 3
    k_gemm10    <<<(NN + B - 1) / B, B, 0, stream>>>(hB, W3, bufC, NN);
    k_spmm10    <<<(NN * OUTD + B - 1) / B, B, 0, stream>>>(rowptr, ent, bufC, b3, bufD, NN);
    // pool + log_softmax
    k_poolfin   <<<GG, 256, 0, stream>>>(bufD, gstart, out);
}

// Round 7
// 282.425 us; speedup vs baseline: 3.5426x; 1.0527x over previous
//
#include <hip/hip_runtime.h>
#include <math.h>

#define NN 50000
#define EE 800000
#define GG 64
#define FD 128
#define OUTD 10
#define NB 49           // ceil(NN/1024) scan blocks
#define GB 782          // (NN+63)/64 gemm blocks
#define DB 3125         // EE/256 degree blocks
#define BB 196          // (NN+255)/256 bounds blocks

typedef __attribute__((ext_vector_type(8))) short s8v;    // 8 bf16
typedef __attribute__((ext_vector_type(4))) float f4v;    // 4 f32 acc

static __device__ inline unsigned short f2b(float f) {    // f32 -> bf16 RNE
    unsigned int u = __float_as_uint(f);
    return (unsigned short)((u + 0x7FFFu + ((u >> 16) & 1u)) >> 16);
}

// packed degree accumulator: bits [0,44) = sum(w) in 2^-32 fixed point,
// bits [44,64) = edge count. One u64 atomic per edge; returned old value's
// count field doubles as the edge's rank within its CSR segment.
#define DEG_SCALE 4294967296.0
#define DEG_MASK  ((1ull << 44) - 1)

// ---------------- prep: init accumulators, zero scan flags, transpose weights ----------------

__global__ void k_prep(unsigned long long* packed, const float* __restrict__ W1,
                       const float* __restrict__ W2, unsigned short* __restrict__ Wt1,
                       unsigned short* __restrict__ Wt2, int* __restrict__ bflag, int n) {
    int i = blockIdx.x * blockDim.x + threadIdx.x;
    if (i < n) packed[i] = (1ull << 44) | (1ull << 32);   // cnt=1, deg=1.0 (self-loop)
    if (i < FD * FD) {
        int nn = i >> 7, k = i & 127;
        Wt1[i] = f2b(W1[k * FD + nn]);
        Wt2[i] = f2b(W2[k * FD + nn]);
    }
    if (i < NB) bflag[i] = 0;    // workspace is poisoned 0xAA -> must zero flags
}

// ---------------- mega kernel 1: gemm1 (x f32 -> hA) || degree atomics || bounds ----------------

static __device__ inline void gemm_f32in_body(int bid, const float* __restrict__ A,
        const unsigned short* __restrict__ Wt, unsigned short* __restrict__ out, int n) {
    int tid = threadIdx.x;
    int wave = tid >> 6, lane = tid & 63;
    int quad = lane >> 4, c16 = lane & 15;
    int rowbase = bid * 64 + wave * 16;
    int rowA = rowbase + c16;
    if (rowA >= n) rowA = n - 1;
    f4v acc[8];
    #pragma unroll
    for (int t = 0; t < 8; ++t) acc[t] = (f4v){0.f, 0.f, 0.f, 0.f};
    #pragma unroll
    for (int k0 = 0; k0 < 128; k0 += 32) {
        const float* ap = A + (size_t)rowA * FD + k0 + quad * 8;
        float4 a0 = *(const float4*)ap;
        float4 a1 = *(const float4*)(ap + 4);
        s8v a;
        a[0] = (short)f2b(a0.x); a[1] = (short)f2b(a0.y);
        a[2] = (short)f2b(a0.z); a[3] = (short)f2b(a0.w);
        a[4] = (short)f2b(a1.x); a[5] = (short)f2b(a1.y);
        a[6] = (short)f2b(a1.z); a[7] = (short)f2b(a1.w);
        #pragma unroll
        for (int t = 0; t < 8; ++t) {
            s8v b = *(const s8v*)(Wt + (size_t)(t * 16 + c16) * FD + k0 + quad * 8);
            acc[t] = __builtin_amdgcn_mfma_f32_16x16x32_bf16(a, b, acc[t], 0, 0, 0);
        }
    }
    #pragma unroll
    for (int t = 0; t < 8; ++t) {
        #pragma unroll
        for (int r = 0; r < 4; ++r) {
            int row = rowbase + quad * 4 + r;
            if (row < n) out[(size_t)row * FD + t * 16 + c16] = f2b(acc[t][r]);
        }
    }
}

__global__ __launch_bounds__(256) void k_mega1(const float* __restrict__ x,
        const unsigned short* __restrict__ Wt1, unsigned short* __restrict__ hA,
        const int* __restrict__ dst, const float* __restrict__ ew,
        unsigned long long* packed, unsigned* __restrict__ rank,
        const int* __restrict__ batch, int* __restrict__ gstart) {
    int b = blockIdx.x;
    if (b < GB) {
        gemm_f32in_body(b, x, Wt1, hA, NN);
    } else if (b < GB + DB) {
        int i = (b - GB) * 256 + threadIdx.x;
        if (i < EE) {
            unsigned long long q = (unsigned long long)((double)ew[i] * DEG_SCALE + 0.5);
            unsigned long long old = atomicAdd(&packed[dst[i]], (1ull << 44) | q);
            rank[i] = (unsigned)(old >> 44) - 1u;
        }
    } else {
        int i = (b - GB - DB) * 256 + threadIdx.x;
        if (i < NN) {
            int bb = batch[i];
            int bp = (i == 0) ? -1 : batch[i - 1];
            for (int g = bp + 1; g <= bb; ++g) gstart[g] = i;
            if (i == NN - 1)
                for (int g = bb + 1; g <= GG; ++g) gstart[g] = NN;
        }
    }
}

// ---------------- single-kernel scan (decoupled lookback, NB=49 blocks co-resident) ----------------
// also computes dinv and writes the self-loop CSR entry

__global__ __launch_bounds__(1024) void k_scan(const unsigned long long* __restrict__ packed,
        int* __restrict__ rowptr, float* __restrict__ dinv, uint2* __restrict__ ent,
        int* __restrict__ bsum, int* __restrict__ bflag, int n) {
    __shared__ int wtot[16];
    __shared__ int sbase_sh;
    int tid = threadIdx.x;
    int bid = blockIdx.x;
    int i = bid * 1024 + tid;
    int lane = tid & 63, wv = tid >> 6;

    int v = 0;
    float di = 0.0f;
    if (i < n) {
        unsigned long long p = packed[i];
        v = (int)(p >> 44);
        float deg = (float)((double)(p & DEG_MASK) * (1.0 / DEG_SCALE));
        di = 1.0f / sqrtf(deg);
        dinv[i] = di;
    }
    int s = v;
    #pragma unroll
    for (int off = 1; off < 64; off <<= 1) {
        int u = __shfl_up(s, off, 64);
        if (lane >= off) s += u;
    }
    if (lane == 63) wtot[wv] = s;
    __syncthreads();

    int btot = 0;
    #pragma unroll
    for (int j = 0; j < 16; ++j) btot += wtot[j];
    // publish this block's aggregate (release)
    if (tid == 0) {
        bsum[bid] = btot;
        __hip_atomic_store(&bflag[bid], 1, __ATOMIC_RELEASE, __HIP_MEMORY_SCOPE_AGENT);
    }
    // lookback: wave 0 sums aggregates of all predecessor blocks
    if (tid < 64) {
        int acc = 0;
        if (tid < bid) {
            while (__hip_atomic_load(&bflag[tid], __ATOMIC_ACQUIRE,
                                     __HIP_MEMORY_SCOPE_AGENT) == 0) {}
            acc = bsum[tid];
        }
        #pragma unroll
        for (int off = 32; off >= 1; off >>= 1) acc += __shfl_xor(acc, off, 64);
        if (tid == 0) sbase_sh = acc;
    }
    __syncthreads();
    int base = sbase_sh;

    int wpre = 0;
    for (int j = 0; j < wv; ++j) wpre += wtot[j];
    if (i < n) {
        int r = base + wpre + (s - v);            // global exclusive prefix
        rowptr[i] = r;
        ent[r + v - 1] = make_uint2((unsigned)i, __float_as_uint(di * di));  // self-loop
    }
    if (bid == NB - 1 && tid == 0) rowptr[n] = base + btot;
}

// atomic-free scatter: pos = rowptr[d] + rank
__global__ void k_fill(const int* __restrict__ src, const int* __restrict__ dst,
                       const float* __restrict__ w, const float* __restrict__ dinv,
                       const int* __restrict__ rowptr, const unsigned* __restrict__ rank,
                       uint2* __restrict__ ent, int e) {
    int i = blockIdx.x * blockDim.x + threadIdx.x;
    if (i >= e) return;
    int s = src[i], d = dst[i];
    int pos = rowptr[d] + (int)rank[i];
    float v = dinv[s] * w[i] * dinv[d];
    ent[pos] = make_uint2((unsigned)s, __float_as_uint(v));
}

// ---------------- dense transform: bf16 MFMA GEMM (bf16 in) ----------------

__global__ __launch_bounds__(256) void k_gemm_bf(const unsigned short* __restrict__ A,
        const unsigned short* __restrict__ Wt, unsigned short* __restrict__ out, int n) {
    int tid = threadIdx.x;
    int wave = tid >> 6, lane = tid & 63;
    int quad = lane >> 4, c16 = lane & 15;
    int rowbase = blockIdx.x * 64 + wave * 16;
    int rowA = rowbase + c16;
    if (rowA >= n) rowA = n - 1;
    f4v acc[8];
    #pragma unroll
    for (int t = 0; t < 8; ++t) acc[t] = (f4v){0.f, 0.f, 0.f, 0.f};
    #pragma unroll
    for (int k0 = 0; k0 < 128; k0 += 32) {
        s8v a = *(const s8v*)(A + (size_t)rowA * FD + k0 + quad * 8);
        #pragma unroll
        for (int t = 0; t < 8; ++t) {
            s8v b = *(const s8v*)(Wt + (size_t)(t * 16 + c16) * FD + k0 + quad * 8);
            acc[t] = __builtin_amdgcn_mfma_f32_16x16x32_bf16(a, b, acc[t], 0, 0, 0);
        }
    }
    #pragma unroll
    for (int t = 0; t < 8; ++t) {
        #pragma unroll
        for (int r = 0; r < 4; ++r) {
            int row = rowbase + quad * 4 + r;
            if (row < n) out[(size_t)row * FD + t * 16 + c16] = f2b(acc[t][r]);
        }
    }
}

// out[n][10] = A[n][128] @ W[128][10], A bf16, W f32 (LDS), out f32
__global__ void k_gemm10(const unsigned short* __restrict__ A, const float* __restrict__ W,
                         float* __restrict__ out, int n) {
    __shared__ float Ws[FD * OUTD];
    int tid = threadIdx.x;
    for (int i = tid; i < FD * OUTD; i += blockDim.x) Ws[i] = W[i];
    __syncthreads();
    int i = blockIdx.x * blockDim.x + tid;
    if (i >= n) return;
    float acc[OUTD];
    #pragma unroll
    for (int c = 0; c < OUTD; ++c) acc[c] = 0.0f;
    const unsigned short* a = A + (size_t)i * FD;
    for (int k0 = 0; k0 < FD; k0 += 8) {
        uint4 t = *(const uint4*)(a + k0);
        float av[8];
        av[0] = __uint_as_float(t.x << 16); av[1] = __uint_as_float(t.x & 0xFFFF0000u);
        av[2] = __uint_as_float(t.y << 16); av[3] = __uint_as_float(t.y & 0xFFFF0000u);
        av[4] = __uint_as_float(t.z << 16); av[5] = __uint_as_float(t.z & 0xFFFF0000u);
        av[6] = __uint_as_float(t.w << 16); av[7] = __uint_as_float(t.w & 0xFFFF0000u);
        #pragma unroll
        for (int j = 0; j < 8; ++j)
            #pragma unroll
            for (int c = 0; c < OUTD; ++c) acc[c] += av[j] * Ws[(k0 + j) * OUTD + c];
    }
    float* o = out + (size_t)i * OUTD;
    #pragma unroll
    for (int c = 0; c < OUTD; ++c) o[c] = acc[c];
}

// ---------------- sparse aggregation, bf16 features ----------------
// one wave per node; 16 edges in flight per iter (4x unroll of 4 groups x 16B)
__global__ __launch_bounds__(256) void k_spmm_bf(const int* __restrict__ rowptr,
        const uint2* __restrict__ ent, const unsigned short* __restrict__ tin,
        const float* __restrict__ bias, unsigned short* __restrict__ out,
        int n, int dorelu) {
    int w = (blockIdx.x * blockDim.x + threadIdx.x) >> 6;
    int lane = threadIdx.x & 63;
    if (w >= n) return;
    int c = lane & 15, g = lane >> 4;
    int beg = rowptr[w], end = rowptr[w + 1];
    float acc[8];
    #pragma unroll
    for (int j = 0; j < 8; ++j) acc[j] = 0.0f;
    for (int e0 = beg; e0 < end; e0 += 16) {
        uint2 en[4];
        uint4 t[4];
        #pragma unroll
        for (int u = 0; u < 4; ++u) {
            int e = e0 + 4 * u + g;
            en[u] = (e < end) ? ent[e] : make_uint2(0u, 0u);
        }
        #pragma unroll
        for (int u = 0; u < 4; ++u)
            t[u] = *(const uint4*)(tin + (size_t)en[u].x * FD + c * 8);
        #pragma unroll
        for (int u = 0; u < 4; ++u) {
            float v = __uint_as_float(en[u].y);
            acc[0] += v * __uint_as_float(t[u].x << 16);
            acc[1] += v * __uint_as_float(t[u].x & 0xFFFF0000u);
            acc[2] += v * __uint_as_float(t[u].y << 16);
            acc[3] += v * __uint_as_float(t[u].y & 0xFFFF0000u);
            acc[4] += v * __uint_as_float(t[u].z << 16);
            acc[5] += v * __uint_as_float(t[u].z & 0xFFFF0000u);
            acc[6] += v * __uint_as_float(t[u].w << 16);
            acc[7] += v * __uint_as_float(t[u].w & 0xFFFF0000u);
        }
    }
    #pragma unroll
    for (int j = 0; j < 8; ++j) {
        acc[j] += __shfl_xor(acc[j], 16, 64);
        acc[j] += __shfl_xor(acc[j], 32, 64);
    }
    if (g == 0) {
        uint4 r;
        float o[8];
        #pragma unroll
        for (int j = 0; j < 8; ++j) {
            float x = acc[j] + bias[c * 8 + j];
            o[j] = dorelu ? fmaxf(x, 0.0f) : x;
        }
        r.x = (unsigned)f2b(o[0]) | ((unsigned)f2b(o[1]) << 16);
        r.y = (unsigned)f2b(o[2]) | ((unsigned)f2b(o[3]) << 16);
        r.z = (unsigned)f2b(o[4]) | ((unsigned)f2b(o[5]) << 16);
        r.w = (unsigned)f2b(o[6]) | ((unsigned)f2b(o[7]) << 16);
        *(uint4*)(out + (size_t)w * FD + c * 8) = r;
    }
}

// one thread per (node, feature), 10 features, f32 (input 2 MB -> L2-resident)
__global__ void k_spmm10(const int* __restrict__ rowptr, const uint2* __restrict__ ent,
        const float* __restrict__ tin, const float* __restrict__ bias,
        float* __restrict__ out, int n) {
    int t = blockIdx.x * blockDim.x + threadIdx.x;
    int node = t / OUTD;
    int c = t - node * OUTD;
    if (node >= n) return;
    int beg = rowptr[node], end = rowptr[node + 1];
    float acc = 0.0f;
    for (int e = beg; e < end; ++e) {
        uint2 en = ent[e];
        acc += __uint_as_float(en.y) * tin[(size_t)en.x * OUTD + c];
    }
    out[(size_t)node * OUTD + c] = acc + bias[c];
}

// ---------------- pooling + log_softmax (1 block/graph) ----------------

__global__ __launch_bounds__(256) void k_poolfin(const float* __restrict__ h,
        const int* __restrict__ gstart, float* __restrict__ out) {
    int g = blockIdx.x;
    int beg = gstart[g], end = gstart[g + 1];
    int tid = threadIdx.x;
    int lane = tid & 63, wv = tid >> 6;
    float acc[OUTD];
    #pragma unroll
    for (int c = 0; c < OUTD; ++c) acc[c] = 0.0f;
    for (int i = beg + tid; i < end; i += 256) {
        const float* hp = h + (size_t)i * OUTD;
        #pragma unroll
        for (int c = 0; c < OUTD; ++c) acc[c] += hp[c];
    }
    #pragma unroll
    for (int off = 32; off >= 1; off >>= 1)
        #pragma unroll
        for (int c = 0; c < OUTD; ++c) acc[c] += __shfl_down(acc[c], off, 64);
    __shared__ float ws[4][OUTD];
    if (lane == 0)
        #pragma unroll
        for (int c = 0; c < OUTD; ++c) ws[wv][c] = acc[c];
    __syncthreads();
    if (tid == 0) {
        float cf = fmaxf((float)(end - beg), 1.0f);
        float v[OUTD], m = -1e30f;
        #pragma unroll
        for (int c = 0; c < OUTD; ++c) {
            v[c] = (ws[0][c] + ws[1][c] + ws[2][c] + ws[3][c]) / cf;
            m = fmaxf(m, v[c]);
        }
        float s = 0.0f;
        #pragma unroll
        for (int c = 0; c < OUTD; ++c) s += expf(v[c] - m);
        float l = logf(s);
        #pragma unroll
        for (int c = 0; c < OUTD; ++c) out[g * OUTD + c] = v[c] - m - l;
    }
}

// ---------------- launcher ----------------

extern "C" void kernel_launch(void* const* d_in, const int* in_sizes, int n_in,
                              void* d_out, int out_size, void* d_ws, size_t ws_size,
                              hipStream_t stream) {
    const float* x   = (const float*)d_in[0];
    const int*   ei  = (const int*)d_in[1];
    const float* ew  = (const float*)d_in[2];
    const int*   bat = (const int*)d_in[3];
    const float* W1  = (const float*)d_in[4];
    const float* b1  = (const float*)d_in[5];
    const float* W2  = (const float*)d_in[6];
    const float* b2  = (const float*)d_in[7];
    const float* W3  = (const float*)d_in[8];
    const float* b3  = (const float*)d_in[9];
    float* out = (float*)d_out;

    const int* src = ei;
    const int* dst = ei + EE;

    char* p = (char*)d_ws;
    auto alloc = [&](size_t bytes) -> void* {
        void* r = (void*)p;
        p += (bytes + 255) & ~(size_t)255;
        return r;
    };
    unsigned long long* packed = (unsigned long long*)alloc((size_t)NN * 8);
    float*          dinv   = (float*)alloc((size_t)NN * 4);
    int*            rowptr = (int*)  alloc((size_t)(NN + 1) * 4);
    unsigned*       rank   = (unsigned*)alloc((size_t)EE * 4);
    uint2*          ent    = (uint2*)alloc((size_t)(EE + NN) * 8);
    unsigned short* Wt1    = (unsigned short*)alloc((size_t)FD * FD * 2);
    unsigned short* Wt2    = (unsigned short*)alloc((size_t)FD * FD * 2);
    unsigned short* hA     = (unsigned short*)alloc((size_t)NN * FD * 2);
    unsigned short* hB     = (unsigned short*)alloc((size_t)NN * FD * 2);
    float*          bufC   = (float*)alloc((size_t)NN * OUTD * 4);
    float*          bufD   = (float*)alloc((size_t)NN * OUTD * 4);
    int*            bsum   = (int*)  alloc((size_t)NB * 4);
    int*            bflag  = (int*)  alloc((size_t)NB * 4);
    int*            gstart = (int*)  alloc((size_t)(GG + 1) * 4);
    (void)ws_size; (void)in_sizes; (void)n_in; (void)out_size;

    const int B = 256;
    // prep (also zeroes the scan flags -- workspace is poisoned each call)
    k_prep <<<(NN + B - 1) / B, B, 0, stream>>>(packed, W1, W2, Wt1, Wt2, bflag, NN);
    // fused: layer-1 GEMM || degree atomics+rank || graph bounds
    k_mega1<<<GB + DB + BB, B, 0, stream>>>(x, Wt1, hA, dst, ew, packed, rank, bat, gstart);
    // single-kernel scan (+dinv, +self-loop entries)
    k_scan <<<NB, 1024, 0, stream>>>(packed, rowptr, dinv, ent, bsum, bflag, NN);
    // CSR fill (atomic-free)
    k_fill <<<(EE + B - 1) / B, B, 0, stream>>>(src, dst, ew, dinv, rowptr, rank, ent, EE);

    // layer 1 aggregation
    k_spmm_bf<<<(NN * 64 + B - 1) / B, B, 0, stream>>>(rowptr, ent, hA, b1, hB, NN, 1);
    // layer 2
    k_gemm_bf<<<GB, B, 0, stream>>>(hB, Wt2, hA, NN);
    k_spmm_bf<<<(NN * 64 + B - 1) / B, B, 0, stream>>>(rowptr, ent, hA, b2, hB, NN, 1);
    // layer 3
    k_gemm10 <<<(NN + B - 1) / B, B, 0, stream>>>(hB, W3, bufC, NN);
    k_spmm10 <<<(NN * OUTD + B - 1) / B, B, 0, stream>>>(rowptr, ent, bufC, b3, bufD, NN);
    // pool + log_softmax
    k_poolfin<<<GG, 256, 0, stream>>>(bufD, gstart, out);
}